// Round 9
// baseline (279.180 us; speedup 1.0000x reference)
//
#include <hip/hip_runtime.h>
#include <hip/hip_fp16.h>
#include <math.h>

#define N_NODES 100000
#define N_EDGES 1600000
#define IN_FEAT 128
#define HIDDEN 64
#define N_CLASSES 16

#define TMG 128
#define GBLKG ((N_NODES + TMG - 1) / TMG)  // 782

#define NBUK 196                        // buckets of 512 nodes (dst>>9)
#define CB 4096                         // edges per partition block
#define NCB ((N_EDGES + CB - 1) / CB)   // 391

// pack: src in bits 0..16 (src<2^17), local dst (dst&511) in bits 17..25
#define PACK(s, d)  ((s) | (((d) & 511) << 17))
#define P_SRC(p)    ((p) & 0x1FFFF)
#define P_LOC(p)    (((unsigned)(p)) >> 17)

// ---------------- deterministic two-pass bucket partition ----------------
// No global atomics anywhere (same-address atomic rendezvous costs
// ~28ns x chain-length; was 44us in bukhist, ~10us in coarse).

__global__ __launch_bounds__(256) void count_k(const int* __restrict__ dst,
                                               int* __restrict__ blk_cnt) {
    __shared__ int hist[NBUK + 4];
    int tid = threadIdx.x;
    if (tid < NBUK) hist[tid] = 0;
    __syncthreads();
    int eb = blockIdx.x * CB;
    #pragma unroll
    for (int q = 0; q < 4; ++q) {
        int e4 = (eb >> 2) + tid + q * 256;
        if (e4 * 4 < N_EDGES) {   // N_EDGES % 4 == 0
            int4 d4 = ((const int4*)dst)[e4];
            atomicAdd(&hist[d4.x >> 9], 1);
            atomicAdd(&hist[d4.y >> 9], 1);
            atomicAdd(&hist[d4.z >> 9], 1);
            atomicAdd(&hist[d4.w >> 9], 1);
        }
    }
    __syncthreads();
    if (tid < NBUK) blk_cnt[blockIdx.x * NBUK + tid] = hist[tid];
}

// one block per bucket: exclusive prefix of cnt[*][b] over the 391 blocks,
// in place; column total -> coltot[b].
__global__ __launch_bounds__(512) void colscan_k(int* __restrict__ blk_cnt,
                                                 int* __restrict__ coltot) {
    __shared__ int sm[512];
    int b = blockIdx.x;
    int t = threadIdx.x;
    int v = (t < NCB) ? blk_cnt[t * NBUK + b] : 0;
    sm[t] = v;
    __syncthreads();
    for (int s = 1; s < 512; s <<= 1) {
        int add = (t >= s) ? sm[t - s] : 0;
        __syncthreads();
        sm[t] += add;
        __syncthreads();
    }
    if (t < NCB) blk_cnt[t * NBUK + b] = sm[t] - v;   // exclusive colpre
    if (t == NCB - 1) coltot[b] = sm[t];
}

// rank via LDS atomics from deterministic base; direct scatter of PACKED
// edges. buk_off re-derived in-kernel from coltot (196-scan in LDS).
__global__ __launch_bounds__(256) void place_k(const int* __restrict__ src,
                                               const int* __restrict__ dst,
                                               const int* __restrict__ colpre,
                                               const int* __restrict__ coltot,
                                               int* __restrict__ pairs_p) {
    __shared__ int sm[256];
    __shared__ int cur[NBUK + 4];
    int tid = threadIdx.x;
    int blk = blockIdx.x;
    int v = (tid < NBUK) ? coltot[tid] : 0;
    sm[tid] = v;
    __syncthreads();
    for (int s = 1; s < 256; s <<= 1) {
        int add = (tid >= s) ? sm[tid - s] : 0;
        __syncthreads();
        sm[tid] += add;
        __syncthreads();
    }
    if (tid < NBUK) cur[tid] = (sm[tid] - v) + colpre[blk * NBUK + tid];
    __syncthreads();
    int eb = blk * CB;
    #pragma unroll
    for (int q = 0; q < 4; ++q) {
        int e4 = (eb >> 2) + tid + q * 256;
        if (e4 * 4 < N_EDGES) {
            int4 s4 = ((const int4*)src)[e4];
            int4 d4 = ((const int4*)dst)[e4];
            int r;
            r = atomicAdd(&cur[d4.x >> 9], 1); pairs_p[r] = PACK(s4.x, d4.x);
            r = atomicAdd(&cur[d4.y >> 9], 1); pairs_p[r] = PACK(s4.y, d4.y);
            r = atomicAdd(&cur[d4.z >> 9], 1); pairs_p[r] = PACK(s4.z, d4.z);
            r = atomicAdd(&cur[d4.w >> 9], 1); pairs_p[r] = PACK(s4.w, d4.w);
        }
    }
}

// ---------------- fine: SINGLE-PASS per-bucket CSR build ----------------

#define FCAP 12288

__global__ __launch_bounds__(256) void fine2_k(const int* __restrict__ pairs_p,
                                               const int* __restrict__ coltot,
                                               int* __restrict__ csr_src,
                                               int* __restrict__ row_ptr,
                                               float* __restrict__ dinv) {
    __shared__ int stage[FCAP];
    __shared__ int cnt[512];
    __shared__ int psc[256];
    __shared__ int cur[512];
    __shared__ int sm[256];
    __shared__ int sE0, sE1;
    int b = blockIdx.x;
    int node0 = b * 512;
    int nn = N_NODES - node0;
    if (nn > 512) nn = 512;
    int tid = threadIdx.x;

    int v = (tid < NBUK) ? coltot[tid] : 0;
    sm[tid] = v;
    cnt[tid] = 0; cnt[tid + 256] = 0;
    __syncthreads();
    for (int s = 1; s < 256; s <<= 1) {
        int add = (tid >= s) ? sm[tid - s] : 0;
        __syncthreads();
        sm[tid] += add;
        __syncthreads();
    }
    if (tid == b) { sE1 = sm[tid]; sE0 = sm[tid] - v; }
    __syncthreads();

    int e0 = sE0;
    int e1 = sE1;
    int nE = e1 - e0;
    bool inlds = (nE <= FCAP);

    if (inlds) {
        for (int e = e0 + tid; e < e1; e += 256) {
            int p = pairs_p[e];
            stage[e - e0] = p;
            atomicAdd(&cnt[P_LOC(p)], 1);
        }
    } else {
        for (int e = e0 + tid; e < e1; e += 256)
            atomicAdd(&cnt[P_LOC(pairs_p[e])], 1);
    }
    __syncthreads();

    int c0 = cnt[2 * tid], c1 = cnt[2 * tid + 1];
    int p = c0 + c1;
    psc[tid] = p;
    __syncthreads();
    for (int s = 1; s < 256; s <<= 1) {
        int add = (tid >= s) ? psc[tid - s] : 0;
        __syncthreads();
        psc[tid] += add;
        __syncthreads();
    }
    int excl = psc[tid] - p;
    int g0 = e0 + excl;
    int g1 = g0 + c0;
    cur[2 * tid] = g0;
    cur[2 * tid + 1] = g1;
    if (2 * tid < nn) {
        row_ptr[node0 + 2 * tid] = g0;
        dinv[node0 + 2 * tid] = 1.0f / sqrtf((float)(c0 + 1));
    }
    if (2 * tid + 1 < nn) {
        row_ptr[node0 + 2 * tid + 1] = g1;
        dinv[node0 + 2 * tid + 1] = 1.0f / sqrtf((float)(c1 + 1));
    }
    if (b == NBUK - 1 && tid == 0) row_ptr[N_NODES] = N_EDGES;
    __syncthreads();

    if (inlds) {
        for (int i = tid; i < nE; i += 256) {
            int pr = stage[i];
            int pos = atomicAdd(&cur[P_LOC(pr)], 1);
            csr_src[pos] = P_SRC(pr);
        }
    } else {
        for (int e = e0 + tid; e < e1; e += 256) {
            int pr = pairs_p[e];
            int pos = atomicAdd(&cur[P_LOC(pr)], 1);
            csr_src[pos] = P_SRC(pr);
        }
    }
}

// ---------------- register-tiled GEMM 1: hws_h = fp16((x @ W1) * dinv[row]) ----------------
// 128-row tile, 8x4 per thread: 48B LDS per 32 FMA (was 32B/16 FMA) -> -25%
// LDS bytes/FMA; 782 blocks, LDS 50KB -> 3 blocks/CU.

__global__ __launch_bounds__(256) void gemm1_tiled_k(const float* __restrict__ x,
                                                     const float* __restrict__ W,
                                                     const float* __restrict__ dinv,
                                                     __half* __restrict__ hws_h) {
    __shared__ float Ws[64][64];       // 16 KB
    __shared__ float xt[64][132];      // K x (128 rows + 4 pad) = 33.8 KB
    int tid = threadIdx.x;
    int row0 = blockIdx.x * TMG;
    int rgrp8 = (tid >> 4) * 8;        // 16 row-groups x 8
    int cgrp4 = (tid & 15) * 4;        // 16 col-groups x 4

    float acc[8][4];
    #pragma unroll
    for (int r = 0; r < 8; ++r)
        #pragma unroll
        for (int c = 0; c < 4; ++c) acc[r][c] = 0.0f;

    for (int k0 = 0; k0 < IN_FEAT; k0 += 64) {
        #pragma unroll
        for (int i = 0; i < 4; ++i) {
            int f4 = tid + i * 256;
            int kk = f4 >> 4, c4 = (f4 & 15) * 4;
            *(float4*)&Ws[kk][c4] = *(const float4*)&W[(size_t)(k0 + kk) * HIDDEN + c4];
        }
        #pragma unroll
        for (int i = 0; i < 8; ++i) {
            int f4 = tid + i * 256;
            int rr = f4 >> 4, kq = (f4 & 15) * 4;
            int row = row0 + rr;
            if (row >= N_NODES) row = N_NODES - 1;
            float4 v = *(const float4*)&x[(size_t)row * IN_FEAT + k0 + kq];
            xt[kq + 0][rr] = v.x; xt[kq + 1][rr] = v.y;
            xt[kq + 2][rr] = v.z; xt[kq + 3][rr] = v.w;
        }
        __syncthreads();

        #pragma unroll 8
        for (int kk = 0; kk < 64; ++kk) {
            float4 a0 = *(const float4*)&xt[kk][rgrp8];
            float4 a1 = *(const float4*)&xt[kk][rgrp8 + 4];
            float4 b = *(const float4*)&Ws[kk][cgrp4];
            acc[0][0] += a0.x * b.x; acc[0][1] += a0.x * b.y; acc[0][2] += a0.x * b.z; acc[0][3] += a0.x * b.w;
            acc[1][0] += a0.y * b.x; acc[1][1] += a0.y * b.y; acc[1][2] += a0.y * b.z; acc[1][3] += a0.y * b.w;
            acc[2][0] += a0.z * b.x; acc[2][1] += a0.z * b.y; acc[2][2] += a0.z * b.z; acc[2][3] += a0.z * b.w;
            acc[3][0] += a0.w * b.x; acc[3][1] += a0.w * b.y; acc[3][2] += a0.w * b.z; acc[3][3] += a0.w * b.w;
            acc[4][0] += a1.x * b.x; acc[4][1] += a1.x * b.y; acc[4][2] += a1.x * b.z; acc[4][3] += a1.x * b.w;
            acc[5][0] += a1.y * b.x; acc[5][1] += a1.y * b.y; acc[5][2] += a1.y * b.z; acc[5][3] += a1.y * b.w;
            acc[6][0] += a1.z * b.x; acc[6][1] += a1.z * b.y; acc[6][2] += a1.z * b.z; acc[6][3] += a1.z * b.w;
            acc[7][0] += a1.w * b.x; acc[7][1] += a1.w * b.y; acc[7][2] += a1.w * b.z; acc[7][3] += a1.w * b.w;
        }
        __syncthreads();
    }

    #pragma unroll
    for (int r = 0; r < 8; ++r) {
        int row = row0 + rgrp8 + r;
        if (row < N_NODES) {
            float dn = dinv[row];
            __half2* ph = (__half2*)&hws_h[(size_t)row * HIDDEN + cgrp4];
            ph[0] = __floats2half2_rn(acc[r][0] * dn, acc[r][1] * dn);
            ph[1] = __floats2half2_rn(acc[r][2] * dn, acc[r][3] * dn);
        }
    }
}

// ---------------- register-tiled GEMM 2: hws_h = fp16((relu(agg) @ W2) * dinv[row]) ----------------

__global__ __launch_bounds__(256) void gemm2_tiled_k(const float* __restrict__ agg,
                                                     const float* __restrict__ W,
                                                     const float* __restrict__ dinv,
                                                     __half* __restrict__ hws_h) {
    __shared__ float Ws[64][64];
    __shared__ float xt[64][132];
    int tid = threadIdx.x;
    int row0 = blockIdx.x * TMG;
    int rgrp8 = (tid >> 4) * 8;
    int cgrp4 = (tid & 15) * 4;

    #pragma unroll
    for (int i = 0; i < 4; ++i) {
        int f4 = tid + i * 256;
        int kk = f4 >> 4, c4 = (f4 & 15) * 4;
        *(float4*)&Ws[kk][c4] = *(const float4*)&W[(size_t)kk * HIDDEN + c4];
    }
    #pragma unroll
    for (int i = 0; i < 8; ++i) {
        int f4 = tid + i * 256;
        int rr = f4 >> 4, kq = (f4 & 15) * 4;
        int row = row0 + rr;
        if (row >= N_NODES) row = N_NODES - 1;
        float4 v = *(const float4*)&agg[(size_t)row * HIDDEN + kq];
        xt[kq + 0][rr] = fmaxf(v.x, 0.f); xt[kq + 1][rr] = fmaxf(v.y, 0.f);
        xt[kq + 2][rr] = fmaxf(v.z, 0.f); xt[kq + 3][rr] = fmaxf(v.w, 0.f);
    }
    __syncthreads();

    float acc[8][4];
    #pragma unroll
    for (int r = 0; r < 8; ++r)
        #pragma unroll
        for (int c = 0; c < 4; ++c) acc[r][c] = 0.0f;

    #pragma unroll 8
    for (int kk = 0; kk < 64; ++kk) {
        float4 a0 = *(const float4*)&xt[kk][rgrp8];
        float4 a1 = *(const float4*)&xt[kk][rgrp8 + 4];
        float4 b = *(const float4*)&Ws[kk][cgrp4];
        acc[0][0] += a0.x * b.x; acc[0][1] += a0.x * b.y; acc[0][2] += a0.x * b.z; acc[0][3] += a0.x * b.w;
        acc[1][0] += a0.y * b.x; acc[1][1] += a0.y * b.y; acc[1][2] += a0.y * b.z; acc[1][3] += a0.y * b.w;
        acc[2][0] += a0.z * b.x; acc[2][1] += a0.z * b.y; acc[2][2] += a0.z * b.z; acc[2][3] += a0.z * b.w;
        acc[3][0] += a0.w * b.x; acc[3][1] += a0.w * b.y; acc[3][2] += a0.w * b.z; acc[3][3] += a0.w * b.w;
        acc[4][0] += a1.x * b.x; acc[4][1] += a1.x * b.y; acc[4][2] += a1.x * b.z; acc[4][3] += a1.x * b.w;
        acc[5][0] += a1.y * b.x; acc[5][1] += a1.y * b.y; acc[5][2] += a1.y * b.z; acc[5][3] += a1.y * b.w;
        acc[6][0] += a1.z * b.x; acc[6][1] += a1.z * b.y; acc[6][2] += a1.z * b.z; acc[6][3] += a1.z * b.w;
        acc[7][0] += a1.w * b.x; acc[7][1] += a1.w * b.y; acc[7][2] += a1.w * b.z; acc[7][3] += a1.w * b.w;
    }

    #pragma unroll
    for (int r = 0; r < 8; ++r) {
        int row = row0 + rgrp8 + r;
        if (row < N_NODES) {
            float dn = dinv[row];
            __half2* ph = (__half2*)&hws_h[(size_t)row * HIDDEN + cgrp4];
            ph[0] = __floats2half2_rn(acc[r][0] * dn, acc[r][1] * dn);
            ph[1] = __floats2half2_rn(acc[r][2] * dn, acc[r][3] * dn);
        }
    }
}

// ---------------- CSR pull core ----------------
// one wave per node, lane = channel, fp16 rows, uniform-base gathers,
// 16-wide gather window (A/B-verified optimum).

#define PULL_BODY(OUT_STMT)                                                  \
    int start = __builtin_amdgcn_readfirstlane(row_ptr[node]);               \
    int end   = __builtin_amdgcn_readfirstlane(row_ptr[node + 1]);           \
    const __half* __restrict__ selfrow = hws_h + ((size_t)node << 6);        \
    float blane = b[lane];                                                   \
    float a0 = __half2float(selfrow[lane]);                                  \
    float dn = dinv[node];                                                   \
    float a1 = 0.f, a2 = 0.f, a3 = 0.f, a4 = 0.f, a5 = 0.f, a6 = 0.f, a7 = 0.f; \
    int base = start;                                                        \
    while (base < end) {                                                     \
        int rem = end - base;                                                \
        int ci = base + lane;                                                \
        int lastci = end - 1;                                                \
        if (ci > lastci) ci = lastci;                                        \
        int idxv = csr_src[ci];                                              \
        int nch = rem < 64 ? rem : 64;                                       \
        for (int j = 0; j < nch; j += 16) {                                  \
            _Pragma("unroll")                                                \
            for (int k = 0; k < 16; ++k) {                                   \
                int jj = j + k;                                              \
                int s = __builtin_amdgcn_readlane(idxv, jj);                 \
                const __half* __restrict__ row = hws_h + ((size_t)s << 6);   \
                float w = (jj < rem) ? 1.f : 0.f;                            \
                float v = __half2float(row[lane]);                           \
                if (k == 0)      a0 += w * v;                                \
                else if (k == 1) a1 += w * v;                                \
                else if (k == 2) a2 += w * v;                                \
                else if (k == 3) a3 += w * v;                                \
                else if (k == 4) a4 += w * v;                                \
                else if (k == 5) a5 += w * v;                                \
                else if (k == 6) a6 += w * v;                                \
                else if (k == 7) a7 += w * v;                                \
                else if (k == 8)  a0 += w * v;                               \
                else if (k == 9)  a1 += w * v;                               \
                else if (k == 10) a2 += w * v;                               \
                else if (k == 11) a3 += w * v;                               \
                else if (k == 12) a4 += w * v;                               \
                else if (k == 13) a5 += w * v;                               \
                else if (k == 14) a6 += w * v;                               \
                else              a7 += w * v;                               \
            }                                                                \
        }                                                                    \
        base += 64;                                                          \
    }                                                                        \
    float sum = ((a0 + a1) + (a2 + a3)) + ((a4 + a5) + (a6 + a7));           \
    float val = blane + dn * sum;                                            \
    OUT_STMT

__global__ __launch_bounds__(256) void pull_k(const int* __restrict__ row_ptr,
                                              const int* __restrict__ csr_src,
                                              const float* __restrict__ dinv,
                                              const __half* __restrict__ hws_h,
                                              const float* __restrict__ b,
                                              float* __restrict__ agg) {
    int node = __builtin_amdgcn_readfirstlane((blockIdx.x * 256 + threadIdx.x) >> 6);
    int lane = threadIdx.x & 63;
    if (node >= N_NODES) return;
    PULL_BODY({ float* __restrict__ outrow = agg + ((size_t)node << 6);
                outrow[lane] = val; })
}

// ---------------- fused pull2 + classifier head (barrier-free tail) ----------------
// STRIDE-17 Wls (this round): old Wls[k*16+c] made lanes sharing c hit the
// same bank across kg (4-way x 16 iters = measured 3.2M conflict cycles =
// 32/node). Stride 17: residue (16kg + 17i + c) mod 32 covers all 32 banks
// with exactly 2 lanes each -> 2-way = free.

__global__ __launch_bounds__(256) void pull_head_k(const int* __restrict__ row_ptr,
                                                   const int* __restrict__ csr_src,
                                                   const float* __restrict__ dinv,
                                                   const __half* __restrict__ hws_h,
                                                   const float* __restrict__ b,
                                                   const float* __restrict__ Wl,
                                                   const float* __restrict__ bl,
                                                   float* __restrict__ out) {
    __shared__ float Wls[HIDDEN * 17];         // stride-17 layout, 4.25 KB
    __shared__ float hs[4][68];                // per-wave row, padded
    int tid = threadIdx.x;
    int wid = tid >> 6;
    int lane = tid & 63;
    int node = __builtin_amdgcn_readfirstlane(blockIdx.x * 4 + wid);

    // stage head weights once per block (4 coalesced passes, strided LDS)
    for (int i = tid; i < HIDDEN * N_CLASSES; i += 256) {
        int k = i >> 4, c = i & 15;
        Wls[k * 17 + c] = Wl[i];
    }
    __syncthreads();   // start-aligned: waves haven't diverged yet

    PULL_BODY({ hs[wid][lane] = fmaxf(val, 0.0f); })

    // same-wave LDS ordering: reads below see this wave's writes; no end
    // barrier -> no max-of-4-degree coupling.
    int kg = lane >> 4;        // 0..3
    int c  = lane & 15;
    float acc = 0.f;
    #pragma unroll
    for (int i = 0; i < 16; ++i) {
        int k = kg * 16 + i;
        acc += hs[wid][k] * Wls[k * 17 + c];
    }
    acc += __shfl_xor(acc, 16);
    acc += __shfl_xor(acc, 32);
    if (lane < 16)
        out[(size_t)node * N_CLASSES + lane] = acc + bl[lane];
}

// ---------------- launch ----------------

extern "C" void kernel_launch(void* const* d_in, const int* in_sizes, int n_in,
                              void* d_out, int out_size, void* d_ws, size_t ws_size,
                              hipStream_t stream) {
    const float* x  = (const float*)d_in[0];
    const int*   ei = (const int*)d_in[1];
    const float* W1 = (const float*)d_in[2];
    const float* b1 = (const float*)d_in[3];
    const float* W2 = (const float*)d_in[4];
    const float* b2 = (const float*)d_in[5];
    const float* Wl = (const float*)d_in[6];
    const float* bl = (const float*)d_in[7];
    float* out = (float*)d_out;

    const int* src = ei;
    const int* dst = ei + N_EDGES;

    __half* hws_h  = (__half*)d_ws;                              // N*64 halves (12.8 MB)
    float* agg     = (float*)(hws_h + (size_t)N_NODES * HIDDEN); // N*64 floats (25.6 MB)
    int*   pairs_p = (int*)agg;                                  // packed edges alias agg
    int*   csr_src = (int*)(agg + (size_t)N_NODES * HIDDEN);     // E
    float* dinv    = (float*)(csr_src + N_EDGES);                // N
    int*   row_ptr = (int*)(dinv + N_NODES);                     // N+4
    int*   legacy  = row_ptr + N_NODES + 4;                      // 200 (unused)
    int*   coltot  = legacy + 400;                               // 200
    // 391x196 count/colpre matrix aliases csr_src (csr_src written later by fine2)
    int*   blk_cnt = csr_src;

    // --- CSR build (deterministic, atomic-free partition; 4 kernels) ---
    count_k<<<NCB, 256, 0, stream>>>(dst, blk_cnt);
    colscan_k<<<NBUK, 512, 0, stream>>>(blk_cnt, coltot);
    place_k<<<NCB, 256, 0, stream>>>(src, dst, blk_cnt, coltot, pairs_p);
    fine2_k<<<NBUK, 256, 0, stream>>>(pairs_p, coltot, csr_src, row_ptr, dinv);

    // --- layer 1 ---
    gemm1_tiled_k<<<GBLKG, 256, 0, stream>>>(x, W1, dinv, hws_h);
    pull_k<<<(N_NODES * 64 + 255) / 256, 256, 0, stream>>>(row_ptr, csr_src, dinv,
                                                           hws_h, b1, agg);

    // --- layer 2 (+ fused classifier head) ---
    gemm2_tiled_k<<<GBLKG, 256, 0, stream>>>(agg, W2, dinv, hws_h);
    pull_head_k<<<N_NODES / 4, 256, 0, stream>>>(row_ptr, csr_src, dinv,
                                                 hws_h, b2, Wl, bl, out);
}

// Round 10
// 263.529 us; speedup vs baseline: 1.0594x; 1.0594x over previous
//
#include <hip/hip_runtime.h>
#include <hip/hip_fp16.h>
#include <math.h>

#define N_NODES 100000
#define N_EDGES 1600000
#define IN_FEAT 128
#define HIDDEN 64
#define N_CLASSES 16

#define TM 64
#define GBLK ((N_NODES + TM - 1) / TM)  // 1563

#define NBUK 196                        // buckets of 512 nodes (dst>>9)
#define CB 4096                         // edges per partition block
#define NCB ((N_EDGES + CB - 1) / CB)   // 391

// pack: src in bits 0..16 (src<2^17), local dst (dst&511) in bits 17..25
#define PACK(s, d)  ((s) | (((d) & 511) << 17))
#define P_SRC(p)    ((p) & 0x1FFFF)
#define P_LOC(p)    (((unsigned)(p)) >> 17)

// ---------------- deterministic two-pass bucket partition ----------------
// No global atomics anywhere (same-address atomic rendezvous costs
// ~28ns x chain-length; was 44us in bukhist, ~10us in coarse).

__global__ __launch_bounds__(256) void count_k(const int* __restrict__ dst,
                                               int* __restrict__ blk_cnt) {
    __shared__ int hist[NBUK + 4];
    int tid = threadIdx.x;
    if (tid < NBUK) hist[tid] = 0;
    __syncthreads();
    int eb = blockIdx.x * CB;
    #pragma unroll
    for (int q = 0; q < 4; ++q) {
        int e4 = (eb >> 2) + tid + q * 256;
        if (e4 * 4 < N_EDGES) {   // N_EDGES % 4 == 0
            int4 d4 = ((const int4*)dst)[e4];
            atomicAdd(&hist[d4.x >> 9], 1);
            atomicAdd(&hist[d4.y >> 9], 1);
            atomicAdd(&hist[d4.z >> 9], 1);
            atomicAdd(&hist[d4.w >> 9], 1);
        }
    }
    __syncthreads();
    if (tid < NBUK) blk_cnt[blockIdx.x * NBUK + tid] = hist[tid];
}

// one block per bucket: exclusive prefix of cnt[*][b] over the 391 blocks,
// in place; column total -> coltot[b].
__global__ __launch_bounds__(512) void colscan_k(int* __restrict__ blk_cnt,
                                                 int* __restrict__ coltot) {
    __shared__ int sm[512];
    int b = blockIdx.x;
    int t = threadIdx.x;
    int v = (t < NCB) ? blk_cnt[t * NBUK + b] : 0;
    sm[t] = v;
    __syncthreads();
    for (int s = 1; s < 512; s <<= 1) {
        int add = (t >= s) ? sm[t - s] : 0;
        __syncthreads();
        sm[t] += add;
        __syncthreads();
    }
    if (t < NCB) blk_cnt[t * NBUK + b] = sm[t] - v;   // exclusive colpre
    if (t == NCB - 1) coltot[b] = sm[t];
}

// ---------------- place: deterministic bases + LDS-STAGED ORDERED FLUSH ----------------
// R4-R8 versions scattered 1.6M individual 4B global writes (a wave's 64
// addresses hit up to 64 distinct cachelines -> ~16x transaction
// amplification). Now: sort the block's edges by bucket in LDS (local hist +
// scan + LDS scatter, like the original coarse_k), then flush LINEARLY —
// consecutive stage slots land in per-bucket runs (~21 edges), so each wave
// write instruction touches ~4 lines instead of 64. Bases stay deterministic
// (bukbase from coltot scan + colpre), zero global atomics.

__global__ __launch_bounds__(256) void place_k(const int* __restrict__ src,
                                               const int* __restrict__ dst,
                                               const int* __restrict__ colpre,
                                               const int* __restrict__ coltot,
                                               int* __restrict__ pairs_p) {
    __shared__ int sm[256];
    __shared__ int hist[NBUK + 4], loff[NBUK + 4], gbase[NBUK + 4], cur[NBUK + 4];
    __shared__ int2 stage[CB];   // 32 KB
    int tid = threadIdx.x;
    int blk = blockIdx.x;

    // phase A: bukbase = exclusive scan of coltot; gbase = bukbase + colpre
    int v = (tid < NBUK) ? coltot[tid] : 0;
    sm[tid] = v;
    if (tid < NBUK) hist[tid] = 0;
    __syncthreads();
    for (int s = 1; s < 256; s <<= 1) {
        int add = (tid >= s) ? sm[tid - s] : 0;
        __syncthreads();
        sm[tid] += add;
        __syncthreads();
    }
    if (tid < NBUK) gbase[tid] = (sm[tid] - v) + colpre[blk * NBUK + tid];
    __syncthreads();

    // phase B: load edges, local bucket histogram
    int eb = blk * CB;
    int nvalid = N_EDGES - eb;
    if (nvalid > CB) nvalid = CB;
    int4 s4[4], d4[4];
    #pragma unroll
    for (int q = 0; q < 4; ++q) {
        int e4 = (eb >> 2) + tid + q * 256;
        if (e4 * 4 < N_EDGES) {
            s4[q] = ((const int4*)src)[e4];
            d4[q] = ((const int4*)dst)[e4];
        } else {
            d4[q] = make_int4(-1, -1, -1, -1);
            s4[q] = make_int4(0, 0, 0, 0);
        }
    }
    #pragma unroll
    for (int q = 0; q < 4; ++q) {
        if (d4[q].x >= 0) {
            atomicAdd(&hist[d4[q].x >> 9], 1);
            atomicAdd(&hist[d4[q].y >> 9], 1);
            atomicAdd(&hist[d4[q].z >> 9], 1);
            atomicAdd(&hist[d4[q].w >> 9], 1);
        }
    }
    __syncthreads();

    // phase C: local exclusive scan of hist -> loff, cur
    int v2 = (tid < NBUK) ? hist[tid] : 0;
    sm[tid] = v2;
    __syncthreads();
    for (int s = 1; s < 256; s <<= 1) {
        int add = (tid >= s) ? sm[tid - s] : 0;
        __syncthreads();
        sm[tid] += add;
        __syncthreads();
    }
    if (tid < NBUK) {
        int excl = sm[tid] - v2;
        loff[tid] = excl;
        cur[tid] = excl;
    }
    __syncthreads();

    // phase D: LDS scatter (bucket-sorted)
    #pragma unroll
    for (int q = 0; q < 4; ++q) {
        if (d4[q].x >= 0) {
            int b, r;
            b = d4[q].x >> 9; r = atomicAdd(&cur[b], 1); stage[r] = make_int2(s4[q].x, d4[q].x);
            b = d4[q].y >> 9; r = atomicAdd(&cur[b], 1); stage[r] = make_int2(s4[q].y, d4[q].y);
            b = d4[q].z >> 9; r = atomicAdd(&cur[b], 1); stage[r] = make_int2(s4[q].z, d4[q].z);
            b = d4[q].w >> 9; r = atomicAdd(&cur[b], 1); stage[r] = make_int2(s4[q].w, d4[q].w);
        }
    }
    __syncthreads();

    // phase E: ordered flush — consecutive slots -> mostly-contiguous writes
    for (int i = tid; i < nvalid; i += 256) {
        int2 p = stage[i];
        int b = p.y >> 9;
        pairs_p[gbase[b] + (i - loff[b])] = PACK(p.x, p.y);
    }
}

// ---------------- fine: SINGLE-PASS per-bucket CSR build ----------------

#define FCAP 12288

__global__ __launch_bounds__(256) void fine2_k(const int* __restrict__ pairs_p,
                                               const int* __restrict__ coltot,
                                               int* __restrict__ csr_src,
                                               int* __restrict__ row_ptr,
                                               float* __restrict__ dinv) {
    __shared__ int stage[FCAP];
    __shared__ int cnt[512];
    __shared__ int psc[256];
    __shared__ int cur[512];
    __shared__ int sm[256];
    __shared__ int sE0, sE1;
    int b = blockIdx.x;
    int node0 = b * 512;
    int nn = N_NODES - node0;
    if (nn > 512) nn = 512;
    int tid = threadIdx.x;

    int v = (tid < NBUK) ? coltot[tid] : 0;
    sm[tid] = v;
    cnt[tid] = 0; cnt[tid + 256] = 0;
    __syncthreads();
    for (int s = 1; s < 256; s <<= 1) {
        int add = (tid >= s) ? sm[tid - s] : 0;
        __syncthreads();
        sm[tid] += add;
        __syncthreads();
    }
    if (tid == b) { sE1 = sm[tid]; sE0 = sm[tid] - v; }
    __syncthreads();

    int e0 = sE0;
    int e1 = sE1;
    int nE = e1 - e0;
    bool inlds = (nE <= FCAP);

    if (inlds) {
        for (int e = e0 + tid; e < e1; e += 256) {
            int p = pairs_p[e];
            stage[e - e0] = p;
            atomicAdd(&cnt[P_LOC(p)], 1);
        }
    } else {
        for (int e = e0 + tid; e < e1; e += 256)
            atomicAdd(&cnt[P_LOC(pairs_p[e])], 1);
    }
    __syncthreads();

    int c0 = cnt[2 * tid], c1 = cnt[2 * tid + 1];
    int p = c0 + c1;
    psc[tid] = p;
    __syncthreads();
    for (int s = 1; s < 256; s <<= 1) {
        int add = (tid >= s) ? psc[tid - s] : 0;
        __syncthreads();
        psc[tid] += add;
        __syncthreads();
    }
    int excl = psc[tid] - p;
    int g0 = e0 + excl;
    int g1 = g0 + c0;
    cur[2 * tid] = g0;
    cur[2 * tid + 1] = g1;
    if (2 * tid < nn) {
        row_ptr[node0 + 2 * tid] = g0;
        dinv[node0 + 2 * tid] = 1.0f / sqrtf((float)(c0 + 1));
    }
    if (2 * tid + 1 < nn) {
        row_ptr[node0 + 2 * tid + 1] = g1;
        dinv[node0 + 2 * tid + 1] = 1.0f / sqrtf((float)(c1 + 1));
    }
    if (b == NBUK - 1 && tid == 0) row_ptr[N_NODES] = N_EDGES;
    __syncthreads();

    if (inlds) {
        for (int i = tid; i < nE; i += 256) {
            int pr = stage[i];
            int pos = atomicAdd(&cur[P_LOC(pr)], 1);
            csr_src[pos] = P_SRC(pr);
        }
    } else {
        for (int e = e0 + tid; e < e1; e += 256) {
            int pr = pairs_p[e];
            int pos = atomicAdd(&cur[P_LOC(pr)], 1);
            csr_src[pos] = P_SRC(pr);
        }
    }
}

// ---------------- register-tiled GEMM 1: hws_h = fp16((x @ W1) * dinv[row]) ----------------
// 64-tile 4x4 (reverted: the 128-tile 8x4 variant was net-negative in R8).

__global__ __launch_bounds__(256) void gemm1_tiled_k(const float* __restrict__ x,
                                                     const float* __restrict__ W,
                                                     const float* __restrict__ dinv,
                                                     __half* __restrict__ hws_h) {
    __shared__ float Ws[64][64];
    __shared__ float xt[64][68];
    int tid = threadIdx.x;
    int row0 = blockIdx.x * TM;
    int rgrp4 = (tid >> 4) * 4;
    int cgrp4 = (tid & 15) * 4;

    float acc[4][4];
    #pragma unroll
    for (int r = 0; r < 4; ++r)
        #pragma unroll
        for (int c = 0; c < 4; ++c) acc[r][c] = 0.0f;

    for (int k0 = 0; k0 < IN_FEAT; k0 += 64) {
        #pragma unroll
        for (int i = 0; i < 4; ++i) {
            int f4 = tid + i * 256;
            int kk = f4 >> 4, c4 = (f4 & 15) * 4;
            *(float4*)&Ws[kk][c4] = *(const float4*)&W[(size_t)(k0 + kk) * HIDDEN + c4];
        }
        #pragma unroll
        for (int i = 0; i < 4; ++i) {
            int f4 = tid + i * 256;
            int rr = f4 >> 4, kq = (f4 & 15) * 4;
            int row = row0 + rr;
            if (row >= N_NODES) row = N_NODES - 1;
            float4 v = *(const float4*)&x[(size_t)row * IN_FEAT + k0 + kq];
            xt[kq + 0][rr] = v.x; xt[kq + 1][rr] = v.y;
            xt[kq + 2][rr] = v.z; xt[kq + 3][rr] = v.w;
        }
        __syncthreads();

        #pragma unroll 16
        for (int kk = 0; kk < 64; ++kk) {
            float4 a = *(const float4*)&xt[kk][rgrp4];
            float4 b = *(const float4*)&Ws[kk][cgrp4];
            acc[0][0] += a.x * b.x; acc[0][1] += a.x * b.y; acc[0][2] += a.x * b.z; acc[0][3] += a.x * b.w;
            acc[1][0] += a.y * b.x; acc[1][1] += a.y * b.y; acc[1][2] += a.y * b.z; acc[1][3] += a.y * b.w;
            acc[2][0] += a.z * b.x; acc[2][1] += a.z * b.y; acc[2][2] += a.z * b.z; acc[2][3] += a.z * b.w;
            acc[3][0] += a.w * b.x; acc[3][1] += a.w * b.y; acc[3][2] += a.w * b.z; acc[3][3] += a.w * b.w;
        }
        __syncthreads();
    }

    #pragma unroll
    for (int r = 0; r < 4; ++r) {
        int row = row0 + rgrp4 + r;
        if (row < N_NODES) {
            float dn = dinv[row];
            __half2* ph = (__half2*)&hws_h[(size_t)row * HIDDEN + cgrp4];
            ph[0] = __floats2half2_rn(acc[r][0] * dn, acc[r][1] * dn);
            ph[1] = __floats2half2_rn(acc[r][2] * dn, acc[r][3] * dn);
        }
    }
}

// ---------------- register-tiled GEMM 2: hws_h = fp16((relu(agg) @ W2) * dinv[row]) ----------------

__global__ __launch_bounds__(256) void gemm2_tiled_k(const float* __restrict__ agg,
                                                     const float* __restrict__ W,
                                                     const float* __restrict__ dinv,
                                                     __half* __restrict__ hws_h) {
    __shared__ float Ws[64][64];
    __shared__ float xt[64][68];
    int tid = threadIdx.x;
    int row0 = blockIdx.x * TM;
    int rgrp4 = (tid >> 4) * 4;
    int cgrp4 = (tid & 15) * 4;

    #pragma unroll
    for (int i = 0; i < 4; ++i) {
        int f4 = tid + i * 256;
        int kk = f4 >> 4, c4 = (f4 & 15) * 4;
        *(float4*)&Ws[kk][c4] = *(const float4*)&W[(size_t)kk * HIDDEN + c4];
    }
    #pragma unroll
    for (int i = 0; i < 4; ++i) {
        int f4 = tid + i * 256;
        int rr = f4 >> 4, kq = (f4 & 15) * 4;
        int row = row0 + rr;
        if (row >= N_NODES) row = N_NODES - 1;
        float4 v = *(const float4*)&agg[(size_t)row * HIDDEN + kq];
        xt[kq + 0][rr] = fmaxf(v.x, 0.f); xt[kq + 1][rr] = fmaxf(v.y, 0.f);
        xt[kq + 2][rr] = fmaxf(v.z, 0.f); xt[kq + 3][rr] = fmaxf(v.w, 0.f);
    }
    __syncthreads();

    float acc[4][4];
    #pragma unroll
    for (int r = 0; r < 4; ++r)
        #pragma unroll
        for (int c = 0; c < 4; ++c) acc[r][c] = 0.0f;

    #pragma unroll 16
    for (int kk = 0; kk < 64; ++kk) {
        float4 a = *(const float4*)&xt[kk][rgrp4];
        float4 b = *(const float4*)&Ws[kk][cgrp4];
        acc[0][0] += a.x * b.x; acc[0][1] += a.x * b.y; acc[0][2] += a.x * b.z; acc[0][3] += a.x * b.w;
        acc[1][0] += a.y * b.x; acc[1][1] += a.y * b.y; acc[1][2] += a.y * b.z; acc[1][3] += a.y * b.w;
        acc[2][0] += a.z * b.x; acc[2][1] += a.z * b.y; acc[2][2] += a.z * b.z; acc[2][3] += a.z * b.w;
        acc[3][0] += a.w * b.x; acc[3][1] += a.w * b.y; acc[3][2] += a.w * b.z; acc[3][3] += a.w * b.w;
    }

    #pragma unroll
    for (int r = 0; r < 4; ++r) {
        int row = row0 + rgrp4 + r;
        if (row < N_NODES) {
            float dn = dinv[row];
            __half2* ph = (__half2*)&hws_h[(size_t)row * HIDDEN + cgrp4];
            ph[0] = __floats2half2_rn(acc[r][0] * dn, acc[r][1] * dn);
            ph[1] = __floats2half2_rn(acc[r][2] * dn, acc[r][3] * dn);
        }
    }
}

// ---------------- CSR pull core ----------------
// one wave per node, lane = channel, fp16 rows, uniform-base gathers,
// 16-wide gather window (A/B-verified optimum).

#define PULL_BODY(OUT_STMT)                                                  \
    int start = __builtin_amdgcn_readfirstlane(row_ptr[node]);               \
    int end   = __builtin_amdgcn_readfirstlane(row_ptr[node + 1]);           \
    const __half* __restrict__ selfrow = hws_h + ((size_t)node << 6);        \
    float blane = b[lane];                                                   \
    float a0 = __half2float(selfrow[lane]);                                  \
    float dn = dinv[node];                                                   \
    float a1 = 0.f, a2 = 0.f, a3 = 0.f, a4 = 0.f, a5 = 0.f, a6 = 0.f, a7 = 0.f; \
    int base = start;                                                        \
    while (base < end) {                                                     \
        int rem = end - base;                                                \
        int ci = base + lane;                                                \
        int lastci = end - 1;                                                \
        if (ci > lastci) ci = lastci;                                        \
        int idxv = csr_src[ci];                                              \
        int nch = rem < 64 ? rem : 64;                                       \
        for (int j = 0; j < nch; j += 16) {                                  \
            _Pragma("unroll")                                                \
            for (int k = 0; k < 16; ++k) {                                   \
                int jj = j + k;                                              \
                int s = __builtin_amdgcn_readlane(idxv, jj);                 \
                const __half* __restrict__ row = hws_h + ((size_t)s << 6);   \
                float w = (jj < rem) ? 1.f : 0.f;                            \
                float v = __half2float(row[lane]);                           \
                if (k == 0)      a0 += w * v;                                \
                else if (k == 1) a1 += w * v;                                \
                else if (k == 2) a2 += w * v;                                \
                else if (k == 3) a3 += w * v;                                \
                else if (k == 4) a4 += w * v;                                \
                else if (k == 5) a5 += w * v;                                \
                else if (k == 6) a6 += w * v;                                \
                else if (k == 7) a7 += w * v;                                \
                else if (k == 8)  a0 += w * v;                               \
                else if (k == 9)  a1 += w * v;                               \
                else if (k == 10) a2 += w * v;                               \
                else if (k == 11) a3 += w * v;                               \
                else if (k == 12) a4 += w * v;                               \
                else if (k == 13) a5 += w * v;                               \
                else if (k == 14) a6 += w * v;                               \
                else              a7 += w * v;                               \
            }                                                                \
        }                                                                    \
        base += 64;                                                          \
    }                                                                        \
    float sum = ((a0 + a1) + (a2 + a3)) + ((a4 + a5) + (a6 + a7));           \
    float val = blane + dn * sum;                                            \
    OUT_STMT

__global__ __launch_bounds__(256) void pull_k(const int* __restrict__ row_ptr,
                                              const int* __restrict__ csr_src,
                                              const float* __restrict__ dinv,
                                              const __half* __restrict__ hws_h,
                                              const float* __restrict__ b,
                                              float* __restrict__ agg) {
    int node = __builtin_amdgcn_readfirstlane((blockIdx.x * 256 + threadIdx.x) >> 6);
    int lane = threadIdx.x & 63;
    if (node >= N_NODES) return;
    PULL_BODY({ float* __restrict__ outrow = agg + ((size_t)node << 6);
                outrow[lane] = val; })
}

// ---------------- fused pull2 + classifier head (barrier-free tail) ----------------
// R7 version verbatim (49.8us best measured). Stride-16 Wls: the 4-way tail
// conflict (3.2M cyc) is masked under the gather wall; the stride-17 "fix"
// regressed 10us via codegen perturbation of the hot loop (R8). Keep simple.

__global__ __launch_bounds__(256) void pull_head_k(const int* __restrict__ row_ptr,
                                                   const int* __restrict__ csr_src,
                                                   const float* __restrict__ dinv,
                                                   const __half* __restrict__ hws_h,
                                                   const float* __restrict__ b,
                                                   const float* __restrict__ Wl,
                                                   const float* __restrict__ bl,
                                                   float* __restrict__ out) {
    __shared__ float Wls[HIDDEN * N_CLASSES];  // 4 KB
    __shared__ float hs[4][68];                // per-wave row, padded
    int tid = threadIdx.x;
    int wid = tid >> 6;
    int lane = tid & 63;
    int node = __builtin_amdgcn_readfirstlane(blockIdx.x * 4 + wid);

    // stage head weights once per block (256 threads x float4 = 4 KB exactly)
    ((float4*)Wls)[tid] = ((const float4*)Wl)[tid];
    __syncthreads();   // start-aligned: waves haven't diverged yet

    PULL_BODY({ hs[wid][lane] = fmaxf(val, 0.0f); })

    // same-wave LDS ordering: reads below see this wave's writes; no end
    // barrier -> no max-of-4-degree coupling.
    int kg = lane >> 4;        // 0..3
    int c  = lane & 15;
    float acc = 0.f;
    #pragma unroll
    for (int i = 0; i < 16; ++i) {
        int k = kg * 16 + i;
        acc += hs[wid][k] * Wls[k * N_CLASSES + c];
    }
    acc += __shfl_xor(acc, 16);
    acc += __shfl_xor(acc, 32);
    if (lane < 16)
        out[(size_t)node * N_CLASSES + lane] = acc + bl[lane];
}

// ---------------- launch ----------------

extern "C" void kernel_launch(void* const* d_in, const int* in_sizes, int n_in,
                              void* d_out, int out_size, void* d_ws, size_t ws_size,
                              hipStream_t stream) {
    const float* x  = (const float*)d_in[0];
    const int*   ei = (const int*)d_in[1];
    const float* W1 = (const float*)d_in[2];
    const float* b1 = (const float*)d_in[3];
    const float* W2 = (const float*)d_in[4];
    const float* b2 = (const float*)d_in[5];
    const float* Wl = (const float*)d_in[6];
    const float* bl = (const float*)d_in[7];
    float* out = (float*)d_out;

    const int* src = ei;
    const int* dst = ei + N_EDGES;

    __half* hws_h  = (__half*)d_ws;                              // N*64 halves (12.8 MB)
    float* agg     = (float*)(hws_h + (size_t)N_NODES * HIDDEN); // N*64 floats (25.6 MB)
    int*   pairs_p = (int*)agg;                                  // packed edges alias agg
    int*   csr_src = (int*)(agg + (size_t)N_NODES * HIDDEN);     // E
    float* dinv    = (float*)(csr_src + N_EDGES);                // N
    int*   row_ptr = (int*)(dinv + N_NODES);                     // N+4
    int*   legacy  = row_ptr + N_NODES + 4;                      // 200 (unused)
    int*   coltot  = legacy + 400;                               // 200
    // 391x196 count/colpre matrix aliases csr_src (csr_src written later by fine2)
    int*   blk_cnt = csr_src;

    // --- CSR build (deterministic, atomic-free partition; 4 kernels) ---
    count_k<<<NCB, 256, 0, stream>>>(dst, blk_cnt);
    colscan_k<<<NBUK, 512, 0, stream>>>(blk_cnt, coltot);
    place_k<<<NCB, 256, 0, stream>>>(src, dst, blk_cnt, coltot, pairs_p);
    fine2_k<<<NBUK, 256, 0, stream>>>(pairs_p, coltot, csr_src, row_ptr, dinv);

    // --- layer 1 ---
    gemm1_tiled_k<<<GBLK, 256, 0, stream>>>(x, W1, dinv, hws_h);
    pull_k<<<(N_NODES * 64 + 255) / 256, 256, 0, stream>>>(row_ptr, csr_src, dinv,
                                                           hws_h, b1, agg);

    // --- layer 2 (+ fused classifier head) ---
    gemm2_tiled_k<<<GBLK, 256, 0, stream>>>(agg, W2, dinv, hws_h);
    pull_head_k<<<N_NODES / 4, 256, 0, stream>>>(row_ptr, csr_src, dinv,
                                                 hws_h, b2, Wl, bl, out);
}

// Round 11
// 250.849 us; speedup vs baseline: 1.1129x; 1.0505x over previous
//
#include <hip/hip_runtime.h>
#include <hip/hip_fp16.h>
#include <math.h>

#define N_NODES 100000
#define N_EDGES 1600000
#define IN_FEAT 128
#define HIDDEN 64
#define N_CLASSES 16

#define TM 64
#define GBLK ((N_NODES + TM - 1) / TM)  // 1563

#define NBUK 196                        // buckets of 512 nodes (dst>>9)
#define CB 4096                         // edges per partition block
#define NCB ((N_EDGES + CB - 1) / CB)   // 391

// pack: src in bits 0..16 (src<2^17), local dst (dst&511) in bits 17..25
#define PACK(s, d)  ((s) | (((d) & 511) << 17))
#define P_SRC(p)    ((p) & 0x1FFFF)
#define P_LOC(p)    (((unsigned)(p)) >> 17)

// packed-half types for v_dot2_f32_f16 GEMMs
typedef _Float16 hv2 __attribute__((ext_vector_type(2)));
typedef _Float16 hv8 __attribute__((ext_vector_type(8)));

#if __has_builtin(__builtin_amdgcn_fdot2)
#define FDOT2(a, b, c) __builtin_amdgcn_fdot2((a), (b), (c), false)
#else
#define FDOT2(a, b, c) ((c) + (float)(a)[0] * (float)(b)[0] + (float)(a)[1] * (float)(b)[1])
#endif

// ---------------- deterministic two-pass bucket partition ----------------
// No global atomics anywhere (same-address atomic rendezvous costs
// ~28ns x chain-length; was 44us in bukhist, ~10us in coarse).

__global__ __launch_bounds__(256) void count_k(const int* __restrict__ dst,
                                               int* __restrict__ blk_cnt) {
    __shared__ int hist[NBUK + 4];
    int tid = threadIdx.x;
    if (tid < NBUK) hist[tid] = 0;
    __syncthreads();
    int eb = blockIdx.x * CB;
    #pragma unroll
    for (int q = 0; q < 4; ++q) {
        int e4 = (eb >> 2) + tid + q * 256;
        if (e4 * 4 < N_EDGES) {   // N_EDGES % 4 == 0
            int4 d4 = ((const int4*)dst)[e4];
            atomicAdd(&hist[d4.x >> 9], 1);
            atomicAdd(&hist[d4.y >> 9], 1);
            atomicAdd(&hist[d4.z >> 9], 1);
            atomicAdd(&hist[d4.w >> 9], 1);
        }
    }
    __syncthreads();
    if (tid < NBUK) blk_cnt[blockIdx.x * NBUK + tid] = hist[tid];
}

// one block per bucket: exclusive prefix of cnt[*][b] over the 391 blocks,
// in place; column total -> coltot[b].
__global__ __launch_bounds__(512) void colscan_k(int* __restrict__ blk_cnt,
                                                 int* __restrict__ coltot) {
    __shared__ int sm[512];
    int b = blockIdx.x;
    int t = threadIdx.x;
    int v = (t < NCB) ? blk_cnt[t * NBUK + b] : 0;
    sm[t] = v;
    __syncthreads();
    for (int s = 1; s < 512; s <<= 1) {
        int add = (t >= s) ? sm[t - s] : 0;
        __syncthreads();
        sm[t] += add;
        __syncthreads();
    }
    if (t < NCB) blk_cnt[t * NBUK + b] = sm[t] - v;   // exclusive colpre
    if (t == NCB - 1) coltot[b] = sm[t];
}

// ---------------- place: deterministic bases + LDS-staged ordered flush ----------------

__global__ __launch_bounds__(256) void place_k(const int* __restrict__ src,
                                               const int* __restrict__ dst,
                                               const int* __restrict__ colpre,
                                               const int* __restrict__ coltot,
                                               int* __restrict__ pairs_p) {
    __shared__ int sm[256];
    __shared__ int hist[NBUK + 4], loff[NBUK + 4], gbase[NBUK + 4], cur[NBUK + 4];
    __shared__ int2 stage[CB];   // 32 KB
    int tid = threadIdx.x;
    int blk = blockIdx.x;

    // phase A: bukbase = exclusive scan of coltot; gbase = bukbase + colpre
    int v = (tid < NBUK) ? coltot[tid] : 0;
    sm[tid] = v;
    if (tid < NBUK) hist[tid] = 0;
    __syncthreads();
    for (int s = 1; s < 256; s <<= 1) {
        int add = (tid >= s) ? sm[tid - s] : 0;
        __syncthreads();
        sm[tid] += add;
        __syncthreads();
    }
    if (tid < NBUK) gbase[tid] = (sm[tid] - v) + colpre[blk * NBUK + tid];
    __syncthreads();

    // phase B: load edges, local bucket histogram
    int eb = blk * CB;
    int nvalid = N_EDGES - eb;
    if (nvalid > CB) nvalid = CB;
    int4 s4[4], d4[4];
    #pragma unroll
    for (int q = 0; q < 4; ++q) {
        int e4 = (eb >> 2) + tid + q * 256;
        if (e4 * 4 < N_EDGES) {
            s4[q] = ((const int4*)src)[e4];
            d4[q] = ((const int4*)dst)[e4];
        } else {
            d4[q] = make_int4(-1, -1, -1, -1);
            s4[q] = make_int4(0, 0, 0, 0);
        }
    }
    #pragma unroll
    for (int q = 0; q < 4; ++q) {
        if (d4[q].x >= 0) {
            atomicAdd(&hist[d4[q].x >> 9], 1);
            atomicAdd(&hist[d4[q].y >> 9], 1);
            atomicAdd(&hist[d4[q].z >> 9], 1);
            atomicAdd(&hist[d4[q].w >> 9], 1);
        }
    }
    __syncthreads();

    // phase C: local exclusive scan of hist -> loff, cur
    int v2 = (tid < NBUK) ? hist[tid] : 0;
    sm[tid] = v2;
    __syncthreads();
    for (int s = 1; s < 256; s <<= 1) {
        int add = (tid >= s) ? sm[tid - s] : 0;
        __syncthreads();
        sm[tid] += add;
        __syncthreads();
    }
    if (tid < NBUK) {
        int excl = sm[tid] - v2;
        loff[tid] = excl;
        cur[tid] = excl;
    }
    __syncthreads();

    // phase D: LDS scatter (bucket-sorted)
    #pragma unroll
    for (int q = 0; q < 4; ++q) {
        if (d4[q].x >= 0) {
            int b, r;
            b = d4[q].x >> 9; r = atomicAdd(&cur[b], 1); stage[r] = make_int2(s4[q].x, d4[q].x);
            b = d4[q].y >> 9; r = atomicAdd(&cur[b], 1); stage[r] = make_int2(s4[q].y, d4[q].y);
            b = d4[q].z >> 9; r = atomicAdd(&cur[b], 1); stage[r] = make_int2(s4[q].z, d4[q].z);
            b = d4[q].w >> 9; r = atomicAdd(&cur[b], 1); stage[r] = make_int2(s4[q].w, d4[q].w);
        }
    }
    __syncthreads();

    // phase E: ordered flush — consecutive slots -> mostly-contiguous writes
    for (int i = tid; i < nvalid; i += 256) {
        int2 p = stage[i];
        int b = p.y >> 9;
        pairs_p[gbase[b] + (i - loff[b])] = PACK(p.x, p.y);
    }
}

// ---------------- fine: SINGLE-PASS per-bucket CSR build ----------------

#define FCAP 12288

__global__ __launch_bounds__(256) void fine2_k(const int* __restrict__ pairs_p,
                                               const int* __restrict__ coltot,
                                               int* __restrict__ csr_src,
                                               int* __restrict__ row_ptr,
                                               float* __restrict__ dinv) {
    __shared__ int stage[FCAP];
    __shared__ int cnt[512];
    __shared__ int psc[256];
    __shared__ int cur[512];
    __shared__ int sm[256];
    __shared__ int sE0, sE1;
    int b = blockIdx.x;
    int node0 = b * 512;
    int nn = N_NODES - node0;
    if (nn > 512) nn = 512;
    int tid = threadIdx.x;

    int v = (tid < NBUK) ? coltot[tid] : 0;
    sm[tid] = v;
    cnt[tid] = 0; cnt[tid + 256] = 0;
    __syncthreads();
    for (int s = 1; s < 256; s <<= 1) {
        int add = (tid >= s) ? sm[tid - s] : 0;
        __syncthreads();
        sm[tid] += add;
        __syncthreads();
    }
    if (tid == b) { sE1 = sm[tid]; sE0 = sm[tid] - v; }
    __syncthreads();

    int e0 = sE0;
    int e1 = sE1;
    int nE = e1 - e0;
    bool inlds = (nE <= FCAP);

    if (inlds) {
        for (int e = e0 + tid; e < e1; e += 256) {
            int p = pairs_p[e];
            stage[e - e0] = p;
            atomicAdd(&cnt[P_LOC(p)], 1);
        }
    } else {
        for (int e = e0 + tid; e < e1; e += 256)
            atomicAdd(&cnt[P_LOC(pairs_p[e])], 1);
    }
    __syncthreads();

    int c0 = cnt[2 * tid], c1 = cnt[2 * tid + 1];
    int p = c0 + c1;
    psc[tid] = p;
    __syncthreads();
    for (int s = 1; s < 256; s <<= 1) {
        int add = (tid >= s) ? psc[tid - s] : 0;
        __syncthreads();
        psc[tid] += add;
        __syncthreads();
    }
    int excl = psc[tid] - p;
    int g0 = e0 + excl;
    int g1 = g0 + c0;
    cur[2 * tid] = g0;
    cur[2 * tid + 1] = g1;
    if (2 * tid < nn) {
        row_ptr[node0 + 2 * tid] = g0;
        dinv[node0 + 2 * tid] = 1.0f / sqrtf((float)(c0 + 1));
    }
    if (2 * tid + 1 < nn) {
        row_ptr[node0 + 2 * tid + 1] = g1;
        dinv[node0 + 2 * tid + 1] = 1.0f / sqrtf((float)(c1 + 1));
    }
    if (b == NBUK - 1 && tid == 0) row_ptr[N_NODES] = N_EDGES;
    __syncthreads();

    if (inlds) {
        for (int i = tid; i < nE; i += 256) {
            int pr = stage[i];
            int pos = atomicAdd(&cur[P_LOC(pr)], 1);
            csr_src[pos] = P_SRC(pr);
        }
    } else {
        for (int e = e0 + tid; e < e1; e += 256) {
            int pr = pairs_p[e];
            int pos = atomicAdd(&cur[P_LOC(pr)], 1);
            csr_src[pos] = P_SRC(pr);
        }
    }
}

// ---------------- fdot2 GEMM 1: hws_h = fp16((x @ W1) * dinv[row]) ----------------
// KEY CHANGE (this round): tiles staged as packed half2 k-pairs, inner loop
// uses v_dot2_f32_f16 (fp16 x fp16 exact products, fp32 accumulate). LDS
// bytes/FMA and VALU ops/FLOP both halve vs the fp32 float4 version (which
// was LDS-BW bound: 32B per 16 FMA). Only new error = input round-to-fp16
// (2^-11 rel) — the pipeline already carries all features in fp16.

__global__ __launch_bounds__(256) void gemm1_tiled_k(const float* __restrict__ x,
                                                     const float* __restrict__ W,
                                                     const float* __restrict__ dinv,
                                                     __half* __restrict__ hws_h) {
    __shared__ hv2 Ws2[32][64];   // [k2][c]  = {W[k0+2k2][c], W[k0+2k2+1][c]}   8 KB
    __shared__ hv2 xt2[32][68];   // [k2][row]= {x[row][k0+2k2], x[row][k0+2k2+1]} 8.7 KB
    int tid = threadIdx.x;
    int row0 = blockIdx.x * TM;
    int rgrp4 = (tid >> 4) * 4;
    int cgrp4 = (tid & 15) * 4;

    float acc[4][4];
    #pragma unroll
    for (int r = 0; r < 4; ++r)
        #pragma unroll
        for (int c = 0; c < 4; ++c) acc[r][c] = 0.0f;

    for (int k0 = 0; k0 < IN_FEAT; k0 += 64) {
        // stage W pairs: 512 tasks = 32 k2 x 16 c-quads
        #pragma unroll
        for (int i = 0; i < 2; ++i) {
            int f = tid + i * 256;
            int k2 = f >> 4, c4 = (f & 15) * 4;
            float4 r0 = *(const float4*)&W[(size_t)(k0 + 2 * k2) * HIDDEN + c4];
            float4 r1 = *(const float4*)&W[(size_t)(k0 + 2 * k2 + 1) * HIDDEN + c4];
            hv8 h;
            h[0] = (_Float16)r0.x; h[1] = (_Float16)r1.x;
            h[2] = (_Float16)r0.y; h[3] = (_Float16)r1.y;
            h[4] = (_Float16)r0.z; h[5] = (_Float16)r1.z;
            h[6] = (_Float16)r0.w; h[7] = (_Float16)r1.w;
            *(hv8*)&Ws2[k2][c4] = h;
        }
        // stage x pairs: 1024 tasks = 64 rows x 16 k-quads
        #pragma unroll
        for (int i = 0; i < 4; ++i) {
            int f = tid + i * 256;
            int rr = f >> 4, kq4 = (f & 15) * 4;
            int row = row0 + rr;
            if (row >= N_NODES) row = N_NODES - 1;
            float4 v = *(const float4*)&x[(size_t)row * IN_FEAT + k0 + kq4];
            hv2 ha; ha[0] = (_Float16)v.x; ha[1] = (_Float16)v.y;
            hv2 hb; hb[0] = (_Float16)v.z; hb[1] = (_Float16)v.w;
            xt2[(kq4 >> 1) + 0][rr] = ha;
            xt2[(kq4 >> 1) + 1][rr] = hb;
        }
        __syncthreads();

        #pragma unroll 8
        for (int kk2 = 0; kk2 < 32; ++kk2) {
            hv8 av = *(const hv8*)&xt2[kk2][rgrp4];
            hv8 bv = *(const hv8*)&Ws2[kk2][cgrp4];
            hv2 a0 = __builtin_shufflevector(av, av, 0, 1);
            hv2 a1 = __builtin_shufflevector(av, av, 2, 3);
            hv2 a2 = __builtin_shufflevector(av, av, 4, 5);
            hv2 a3 = __builtin_shufflevector(av, av, 6, 7);
            hv2 b0 = __builtin_shufflevector(bv, bv, 0, 1);
            hv2 b1 = __builtin_shufflevector(bv, bv, 2, 3);
            hv2 b2 = __builtin_shufflevector(bv, bv, 4, 5);
            hv2 b3 = __builtin_shufflevector(bv, bv, 6, 7);
            acc[0][0] = FDOT2(a0, b0, acc[0][0]); acc[0][1] = FDOT2(a0, b1, acc[0][1]);
            acc[0][2] = FDOT2(a0, b2, acc[0][2]); acc[0][3] = FDOT2(a0, b3, acc[0][3]);
            acc[1][0] = FDOT2(a1, b0, acc[1][0]); acc[1][1] = FDOT2(a1, b1, acc[1][1]);
            acc[1][2] = FDOT2(a1, b2, acc[1][2]); acc[1][3] = FDOT2(a1, b3, acc[1][3]);
            acc[2][0] = FDOT2(a2, b0, acc[2][0]); acc[2][1] = FDOT2(a2, b1, acc[2][1]);
            acc[2][2] = FDOT2(a2, b2, acc[2][2]); acc[2][3] = FDOT2(a2, b3, acc[2][3]);
            acc[3][0] = FDOT2(a3, b0, acc[3][0]); acc[3][1] = FDOT2(a3, b1, acc[3][1]);
            acc[3][2] = FDOT2(a3, b2, acc[3][2]); acc[3][3] = FDOT2(a3, b3, acc[3][3]);
        }
        __syncthreads();
    }

    #pragma unroll
    for (int r = 0; r < 4; ++r) {
        int row = row0 + rgrp4 + r;
        if (row < N_NODES) {
            float dn = dinv[row];
            __half2* ph = (__half2*)&hws_h[(size_t)row * HIDDEN + cgrp4];
            ph[0] = __floats2half2_rn(acc[r][0] * dn, acc[r][1] * dn);
            ph[1] = __floats2half2_rn(acc[r][2] * dn, acc[r][3] * dn);
        }
    }
}

// ---------------- fdot2 GEMM 2: hws_h = fp16((relu(agg) @ W2) * dinv[row]) ----------------

__global__ __launch_bounds__(256) void gemm2_tiled_k(const float* __restrict__ agg,
                                                     const float* __restrict__ W,
                                                     const float* __restrict__ dinv,
                                                     __half* __restrict__ hws_h) {
    __shared__ hv2 Ws2[32][64];
    __shared__ hv2 xt2[32][68];
    int tid = threadIdx.x;
    int row0 = blockIdx.x * TM;
    int rgrp4 = (tid >> 4) * 4;
    int cgrp4 = (tid & 15) * 4;

    #pragma unroll
    for (int i = 0; i < 2; ++i) {
        int f = tid + i * 256;
        int k2 = f >> 4, c4 = (f & 15) * 4;
        float4 r0 = *(const float4*)&W[(size_t)(2 * k2) * HIDDEN + c4];
        float4 r1 = *(const float4*)&W[(size_t)(2 * k2 + 1) * HIDDEN + c4];
        hv8 h;
        h[0] = (_Float16)r0.x; h[1] = (_Float16)r1.x;
        h[2] = (_Float16)r0.y; h[3] = (_Float16)r1.y;
        h[4] = (_Float16)r0.z; h[5] = (_Float16)r1.z;
        h[6] = (_Float16)r0.w; h[7] = (_Float16)r1.w;
        *(hv8*)&Ws2[k2][c4] = h;
    }
    #pragma unroll
    for (int i = 0; i < 4; ++i) {
        int f = tid + i * 256;
        int rr = f >> 4, kq4 = (f & 15) * 4;
        int row = row0 + rr;
        if (row >= N_NODES) row = N_NODES - 1;
        float4 v = *(const float4*)&agg[(size_t)row * HIDDEN + kq4];
        hv2 ha; ha[0] = (_Float16)fmaxf(v.x, 0.f); ha[1] = (_Float16)fmaxf(v.y, 0.f);
        hv2 hb; hb[0] = (_Float16)fmaxf(v.z, 0.f); hb[1] = (_Float16)fmaxf(v.w, 0.f);
        xt2[(kq4 >> 1) + 0][rr] = ha;
        xt2[(kq4 >> 1) + 1][rr] = hb;
    }
    __syncthreads();

    float acc[4][4];
    #pragma unroll
    for (int r = 0; r < 4; ++r)
        #pragma unroll
        for (int c = 0; c < 4; ++c) acc[r][c] = 0.0f;

    #pragma unroll 8
    for (int kk2 = 0; kk2 < 32; ++kk2) {
        hv8 av = *(const hv8*)&xt2[kk2][rgrp4];
        hv8 bv = *(const hv8*)&Ws2[kk2][cgrp4];
        hv2 a0 = __builtin_shufflevector(av, av, 0, 1);
        hv2 a1 = __builtin_shufflevector(av, av, 2, 3);
        hv2 a2 = __builtin_shufflevector(av, av, 4, 5);
        hv2 a3 = __builtin_shufflevector(av, av, 6, 7);
        hv2 b0 = __builtin_shufflevector(bv, bv, 0, 1);
        hv2 b1 = __builtin_shufflevector(bv, bv, 2, 3);
        hv2 b2 = __builtin_shufflevector(bv, bv, 4, 5);
        hv2 b3 = __builtin_shufflevector(bv, bv, 6, 7);
        acc[0][0] = FDOT2(a0, b0, acc[0][0]); acc[0][1] = FDOT2(a0, b1, acc[0][1]);
        acc[0][2] = FDOT2(a0, b2, acc[0][2]); acc[0][3] = FDOT2(a0, b3, acc[0][3]);
        acc[1][0] = FDOT2(a1, b0, acc[1][0]); acc[1][1] = FDOT2(a1, b1, acc[1][1]);
        acc[1][2] = FDOT2(a1, b2, acc[1][2]); acc[1][3] = FDOT2(a1, b3, acc[1][3]);
        acc[2][0] = FDOT2(a2, b0, acc[2][0]); acc[2][1] = FDOT2(a2, b1, acc[2][1]);
        acc[2][2] = FDOT2(a2, b2, acc[2][2]); acc[2][3] = FDOT2(a2, b3, acc[2][3]);
        acc[3][0] = FDOT2(a3, b0, acc[3][0]); acc[3][1] = FDOT2(a3, b1, acc[3][1]);
        acc[3][2] = FDOT2(a3, b2, acc[3][2]); acc[3][3] = FDOT2(a3, b3, acc[3][3]);
    }

    #pragma unroll
    for (int r = 0; r < 4; ++r) {
        int row = row0 + rgrp4 + r;
        if (row < N_NODES) {
            float dn = dinv[row];
            __half2* ph = (__half2*)&hws_h[(size_t)row * HIDDEN + cgrp4];
            ph[0] = __floats2half2_rn(acc[r][0] * dn, acc[r][1] * dn);
            ph[1] = __floats2half2_rn(acc[r][2] * dn, acc[r][3] * dn);
        }
    }
}

// ---------------- CSR pull core ----------------
// one wave per node, lane = channel, fp16 rows, uniform-base gathers,
// 16-wide gather window (A/B-verified optimum).

#define PULL_BODY(OUT_STMT)                                                  \
    int start = __builtin_amdgcn_readfirstlane(row_ptr[node]);               \
    int end   = __builtin_amdgcn_readfirstlane(row_ptr[node + 1]);           \
    const __half* __restrict__ selfrow = hws_h + ((size_t)node << 6);        \
    float blane = b[lane];                                                   \
    float a0 = __half2float(selfrow[lane]);                                  \
    float dn = dinv[node];                                                   \
    float a1 = 0.f, a2 = 0.f, a3 = 0.f, a4 = 0.f, a5 = 0.f, a6 = 0.f, a7 = 0.f; \
    int base = start;                                                        \
    while (base < end) {                                                     \
        int rem = end - base;                                                \
        int ci = base + lane;                                                \
        int lastci = end - 1;                                                \
        if (ci > lastci) ci = lastci;                                        \
        int idxv = csr_src[ci];                                              \
        int nch = rem < 64 ? rem : 64;                                       \
        for (int j = 0; j < nch; j += 16) {                                  \
            _Pragma("unroll")                                                \
            for (int k = 0; k < 16; ++k) {                                   \
                int jj = j + k;                                              \
                int s = __builtin_amdgcn_readlane(idxv, jj);                 \
                const __half* __restrict__ row = hws_h + ((size_t)s << 6);   \
                float w = (jj < rem) ? 1.f : 0.f;                            \
                float v = __half2float(row[lane]);                           \
                if (k == 0)      a0 += w * v;                                \
                else if (k == 1) a1 += w * v;                                \
                else if (k == 2) a2 += w * v;                                \
                else if (k == 3) a3 += w * v;                                \
                else if (k == 4) a4 += w * v;                                \
                else if (k == 5) a5 += w * v;                                \
                else if (k == 6) a6 += w * v;                                \
                else if (k == 7) a7 += w * v;                                \
                else if (k == 8)  a0 += w * v;                               \
                else if (k == 9)  a1 += w * v;                               \
                else if (k == 10) a2 += w * v;                               \
                else if (k == 11) a3 += w * v;                               \
                else if (k == 12) a4 += w * v;                               \
                else if (k == 13) a5 += w * v;                               \
                else if (k == 14) a6 += w * v;                               \
                else              a7 += w * v;                               \
            }                                                                \
        }                                                                    \
        base += 64;                                                          \
    }                                                                        \
    float sum = ((a0 + a1) + (a2 + a3)) + ((a4 + a5) + (a6 + a7));           \
    float val = blane + dn * sum;                                            \
    OUT_STMT

__global__ __launch_bounds__(256) void pull_k(const int* __restrict__ row_ptr,
                                              const int* __restrict__ csr_src,
                                              const float* __restrict__ dinv,
                                              const __half* __restrict__ hws_h,
                                              const float* __restrict__ b,
                                              float* __restrict__ agg) {
    int node = __builtin_amdgcn_readfirstlane((blockIdx.x * 256 + threadIdx.x) >> 6);
    int lane = threadIdx.x & 63;
    if (node >= N_NODES) return;
    PULL_BODY({ float* __restrict__ outrow = agg + ((size_t)node << 6);
                outrow[lane] = val; })
}

// ---------------- fused pull2 + classifier head (barrier-free tail) ----------------
// R7 version verbatim (49.5-49.8us best measured). Stride-16 Wls: the 4-way
// tail conflict (3.2M cyc) is masked under the gather wall; the stride-17
// "fix" regressed 10us via codegen perturbation of the hot loop (R8).

__global__ __launch_bounds__(256) void pull_head_k(const int* __restrict__ row_ptr,
                                                   const int* __restrict__ csr_src,
                                                   const float* __restrict__ dinv,
                                                   const __half* __restrict__ hws_h,
                                                   const float* __restrict__ b,
                                                   const float* __restrict__ Wl,
                                                   const float* __restrict__ bl,
                                                   float* __restrict__ out) {
    __shared__ float Wls[HIDDEN * N_CLASSES];  // 4 KB
    __shared__ float hs[4][68];                // per-wave row, padded
    int tid = threadIdx.x;
    int wid = tid >> 6;
    int lane = tid & 63;
    int node = __builtin_amdgcn_readfirstlane(blockIdx.x * 4 + wid);

    // stage head weights once per block (256 threads x float4 = 4 KB exactly)
    ((float4*)Wls)[tid] = ((const float4*)Wl)[tid];
    __syncthreads();   // start-aligned: waves haven't diverged yet

    PULL_BODY({ hs[wid][lane] = fmaxf(val, 0.0f); })

    // same-wave LDS ordering: reads below see this wave's writes; no end
    // barrier -> no max-of-4-degree coupling.
    int kg = lane >> 4;        // 0..3
    int c  = lane & 15;
    float acc = 0.f;
    #pragma unroll
    for (int i = 0; i < 16; ++i) {
        int k = kg * 16 + i;
        acc += hs[wid][k] * Wls[k * N_CLASSES + c];
    }
    acc += __shfl_xor(acc, 16);
    acc += __shfl_xor(acc, 32);
    if (lane < 16)
        out[(size_t)node * N_CLASSES + lane] = acc + bl[lane];
}

// ---------------- launch ----------------

extern "C" void kernel_launch(void* const* d_in, const int* in_sizes, int n_in,
                              void* d_out, int out_size, void* d_ws, size_t ws_size,
                              hipStream_t stream) {
    const float* x  = (const float*)d_in[0];
    const int*   ei = (const int*)d_in[1];
    const float* W1 = (const float*)d_in[2];
    const float* b1 = (const float*)d_in[3];
    const float* W2 = (const float*)d_in[4];
    const float* b2 = (const float*)d_in[5];
    const float* Wl = (const float*)d_in[6];
    const float* bl = (const float*)d_in[7];
    float* out = (float*)d_out;

    const int* src = ei;
    const int* dst = ei + N_EDGES;

    __half* hws_h  = (__half*)d_ws;                              // N*64 halves (12.8 MB)
    float* agg     = (float*)(hws_h + (size_t)N_NODES * HIDDEN); // N*64 floats (25.6 MB)
    int*   pairs_p = (int*)agg;                                  // packed edges alias agg
    int*   csr_src = (int*)(agg + (size_t)N_NODES * HIDDEN);     // E
    float* dinv    = (float*)(csr_src + N_EDGES);                // N
    int*   row_ptr = (int*)(dinv + N_NODES);                     // N+4
    int*   legacy  = row_ptr + N_NODES + 4;                      // 200 (unused)
    int*   coltot  = legacy + 400;                               // 200
    // 391x196 count/colpre matrix aliases csr_src (csr_src written later by fine2)
    int*   blk_cnt = csr_src;

    // --- CSR build (deterministic, atomic-free partition; 4 kernels) ---
    count_k<<<NCB, 256, 0, stream>>>(dst, blk_cnt);
    colscan_k<<<NBUK, 512, 0, stream>>>(blk_cnt, coltot);
    place_k<<<NCB, 256, 0, stream>>>(src, dst, blk_cnt, coltot, pairs_p);
    fine2_k<<<NBUK, 256, 0, stream>>>(pairs_p, coltot, csr_src, row_ptr, dinv);

    // --- layer 1 ---
    gemm1_tiled_k<<<GBLK, 256, 0, stream>>>(x, W1, dinv, hws_h);
    pull_k<<<(N_NODES * 64 + 255) / 256, 256, 0, stream>>>(row_ptr, csr_src, dinv,
                                                           hws_h, b1, agg);

    // --- layer 2 (+ fused classifier head) ---
    gemm2_tiled_k<<<GBLK, 256, 0, stream>>>(agg, W2, dinv, hws_h);
    pull_head_k<<<N_NODES / 4, 256, 0, stream>>>(row_ptr, csr_src, dinv,
                                                 hws_h, b2, Wl, bl, out);
}

// Round 13
// 250.299 us; speedup vs baseline: 1.1154x; 1.0022x over previous
//
#include <hip/hip_runtime.h>
#include <hip/hip_fp16.h>
#include <math.h>

#define N_NODES 100000
#define N_EDGES 1600000
#define IN_FEAT 128
#define HIDDEN 64
#define N_CLASSES 16

#define TM 64
#define GBLK ((N_NODES + TM - 1) / TM)  // 1563

#define NBUK 196                        // buckets of 512 nodes (dst>>9)
#define CB 4096                         // edges per partition block
#define NCB ((N_EDGES + CB - 1) / CB)   // 391

// pack: src in bits 0..16 (src<2^17), local dst (dst&511) in bits 17..25
#define PACK(s, d)  ((s) | (((d) & 511) << 17))
#define P_SRC(p)    ((p) & 0x1FFFF)
#define P_LOC(p)    (((unsigned)(p)) >> 17)

// packed-half types for v_dot2_f32_f16 GEMMs
typedef _Float16 hv2 __attribute__((ext_vector_type(2)));
typedef _Float16 hv8 __attribute__((ext_vector_type(8)));

#if __has_builtin(__builtin_amdgcn_fdot2)
#define FDOT2(a, b, c) __builtin_amdgcn_fdot2((a), (b), (c), false)
#else
#define FDOT2(a, b, c) ((c) + (float)(a)[0] * (float)(b)[0] + (float)(a)[1] * (float)(b)[1])
#endif

// ---------------- deterministic two-pass bucket partition ----------------
// No global atomics anywhere (same-address atomic rendezvous costs
// ~28ns x chain-length; was 44us in bukhist, ~10us in coarse).

__global__ __launch_bounds__(256) void count_k(const int* __restrict__ dst,
                                               int* __restrict__ blk_cnt) {
    __shared__ int hist[NBUK + 4];
    int tid = threadIdx.x;
    if (tid < NBUK) hist[tid] = 0;
    __syncthreads();
    int eb = blockIdx.x * CB;
    #pragma unroll
    for (int q = 0; q < 4; ++q) {
        int e4 = (eb >> 2) + tid + q * 256;
        if (e4 * 4 < N_EDGES) {   // N_EDGES % 4 == 0
            int4 d4 = ((const int4*)dst)[e4];
            atomicAdd(&hist[d4.x >> 9], 1);
            atomicAdd(&hist[d4.y >> 9], 1);
            atomicAdd(&hist[d4.z >> 9], 1);
            atomicAdd(&hist[d4.w >> 9], 1);
        }
    }
    __syncthreads();
    if (tid < NBUK) blk_cnt[blockIdx.x * NBUK + tid] = hist[tid];
}

// one block per bucket: exclusive prefix of cnt[*][b] over the 391 blocks,
// in place; column total -> coltot[b].
__global__ __launch_bounds__(512) void colscan_k(int* __restrict__ blk_cnt,
                                                 int* __restrict__ coltot) {
    __shared__ int sm[512];
    int b = blockIdx.x;
    int t = threadIdx.x;
    int v = (t < NCB) ? blk_cnt[t * NBUK + b] : 0;
    sm[t] = v;
    __syncthreads();
    for (int s = 1; s < 512; s <<= 1) {
        int add = (t >= s) ? sm[t - s] : 0;
        __syncthreads();
        sm[t] += add;
        __syncthreads();
    }
    if (t < NCB) blk_cnt[t * NBUK + b] = sm[t] - v;   // exclusive colpre
    if (t == NCB - 1) coltot[b] = sm[t];
}

// ---------------- place: deterministic bases + LDS-staged ordered flush ----------------

__global__ __launch_bounds__(256) void place_k(const int* __restrict__ src,
                                               const int* __restrict__ dst,
                                               const int* __restrict__ colpre,
                                               const int* __restrict__ coltot,
                                               int* __restrict__ pairs_p) {
    __shared__ int sm[256];
    __shared__ int hist[NBUK + 4], loff[NBUK + 4], gbase[NBUK + 4], cur[NBUK + 4];
    __shared__ int2 stage[CB];   // 32 KB
    int tid = threadIdx.x;
    int blk = blockIdx.x;

    // phase A: bukbase = exclusive scan of coltot; gbase = bukbase + colpre
    int v = (tid < NBUK) ? coltot[tid] : 0;
    sm[tid] = v;
    if (tid < NBUK) hist[tid] = 0;
    __syncthreads();
    for (int s = 1; s < 256; s <<= 1) {
        int add = (tid >= s) ? sm[tid - s] : 0;
        __syncthreads();
        sm[tid] += add;
        __syncthreads();
    }
    if (tid < NBUK) gbase[tid] = (sm[tid] - v) + colpre[blk * NBUK + tid];
    __syncthreads();

    // phase B: load edges, local bucket histogram
    int eb = blk * CB;
    int nvalid = N_EDGES - eb;
    if (nvalid > CB) nvalid = CB;
    int4 s4[4], d4[4];
    #pragma unroll
    for (int q = 0; q < 4; ++q) {
        int e4 = (eb >> 2) + tid + q * 256;
        if (e4 * 4 < N_EDGES) {
            s4[q] = ((const int4*)src)[e4];
            d4[q] = ((const int4*)dst)[e4];
        } else {
            d4[q] = make_int4(-1, -1, -1, -1);
            s4[q] = make_int4(0, 0, 0, 0);
        }
    }
    #pragma unroll
    for (int q = 0; q < 4; ++q) {
        if (d4[q].x >= 0) {
            atomicAdd(&hist[d4[q].x >> 9], 1);
            atomicAdd(&hist[d4[q].y >> 9], 1);
            atomicAdd(&hist[d4[q].z >> 9], 1);
            atomicAdd(&hist[d4[q].w >> 9], 1);
        }
    }
    __syncthreads();

    // phase C: local exclusive scan of hist -> loff, cur
    int v2 = (tid < NBUK) ? hist[tid] : 0;
    sm[tid] = v2;
    __syncthreads();
    for (int s = 1; s < 256; s <<= 1) {
        int add = (tid >= s) ? sm[tid - s] : 0;
        __syncthreads();
        sm[tid] += add;
        __syncthreads();
    }
    if (tid < NBUK) {
        int excl = sm[tid] - v2;
        loff[tid] = excl;
        cur[tid] = excl;
    }
    __syncthreads();

    // phase D: LDS scatter (bucket-sorted)
    #pragma unroll
    for (int q = 0; q < 4; ++q) {
        if (d4[q].x >= 0) {
            int b, r;
            b = d4[q].x >> 9; r = atomicAdd(&cur[b], 1); stage[r] = make_int2(s4[q].x, d4[q].x);
            b = d4[q].y >> 9; r = atomicAdd(&cur[b], 1); stage[r] = make_int2(s4[q].y, d4[q].y);
            b = d4[q].z >> 9; r = atomicAdd(&cur[b], 1); stage[r] = make_int2(s4[q].z, d4[q].z);
            b = d4[q].w >> 9; r = atomicAdd(&cur[b], 1); stage[r] = make_int2(s4[q].w, d4[q].w);
        }
    }
    __syncthreads();

    // phase E: ordered flush — consecutive slots -> mostly-contiguous writes
    for (int i = tid; i < nvalid; i += 256) {
        int2 p = stage[i];
        int b = p.y >> 9;
        pairs_p[gbase[b] + (i - loff[b])] = PACK(p.x, p.y);
    }
}

// ---------------- fine: SINGLE-PASS per-bucket CSR build ----------------

#define FCAP 12288

__global__ __launch_bounds__(256) void fine2_k(const int* __restrict__ pairs_p,
                                               const int* __restrict__ coltot,
                                               int* __restrict__ csr_src,
                                               int* __restrict__ row_ptr,
                                               float* __restrict__ dinv) {
    __shared__ int stage[FCAP];
    __shared__ int cnt[512];
    __shared__ int psc[256];
    __shared__ int cur[512];
    __shared__ int sm[256];
    __shared__ int sE0, sE1;
    int b = blockIdx.x;
    int node0 = b * 512;
    int nn = N_NODES - node0;
    if (nn > 512) nn = 512;
    int tid = threadIdx.x;

    int v = (tid < NBUK) ? coltot[tid] : 0;
    sm[tid] = v;
    cnt[tid] = 0; cnt[tid + 256] = 0;
    __syncthreads();
    for (int s = 1; s < 256; s <<= 1) {
        int add = (tid >= s) ? sm[tid - s] : 0;
        __syncthreads();
        sm[tid] += add;
        __syncthreads();
    }
    if (tid == b) { sE1 = sm[tid]; sE0 = sm[tid] - v; }
    __syncthreads();

    int e0 = sE0;
    int e1 = sE1;
    int nE = e1 - e0;
    bool inlds = (nE <= FCAP);

    if (inlds) {
        for (int e = e0 + tid; e < e1; e += 256) {
            int p = pairs_p[e];
            stage[e - e0] = p;
            atomicAdd(&cnt[P_LOC(p)], 1);
        }
    } else {
        for (int e = e0 + tid; e < e1; e += 256)
            atomicAdd(&cnt[P_LOC(pairs_p[e])], 1);
    }
    __syncthreads();

    int c0 = cnt[2 * tid], c1 = cnt[2 * tid + 1];
    int p = c0 + c1;
    psc[tid] = p;
    __syncthreads();
    for (int s = 1; s < 256; s <<= 1) {
        int add = (tid >= s) ? psc[tid - s] : 0;
        __syncthreads();
        psc[tid] += add;
        __syncthreads();
    }
    int excl = psc[tid] - p;
    int g0 = e0 + excl;
    int g1 = g0 + c0;
    cur[2 * tid] = g0;
    cur[2 * tid + 1] = g1;
    if (2 * tid < nn) {
        row_ptr[node0 + 2 * tid] = g0;
        dinv[node0 + 2 * tid] = 1.0f / sqrtf((float)(c0 + 1));
    }
    if (2 * tid + 1 < nn) {
        row_ptr[node0 + 2 * tid + 1] = g1;
        dinv[node0 + 2 * tid + 1] = 1.0f / sqrtf((float)(c1 + 1));
    }
    if (b == NBUK - 1 && tid == 0) row_ptr[N_NODES] = N_EDGES;
    __syncthreads();

    if (inlds) {
        for (int i = tid; i < nE; i += 256) {
            int pr = stage[i];
            int pos = atomicAdd(&cur[P_LOC(pr)], 1);
            csr_src[pos] = P_SRC(pr);
        }
    } else {
        for (int e = e0 + tid; e < e1; e += 256) {
            int pr = pairs_p[e];
            int pos = atomicAdd(&cur[P_LOC(pr)], 1);
            csr_src[pos] = P_SRC(pr);
        }
    }
}

// ---------------- fdot2 GEMM 1: hws_h = fp16((x @ W1) * dinv[row]) ----------------
// Tiles staged as packed half2 k-pairs; inner loop v_dot2_f32_f16 (fp16
// products exact in fp32, fp32 accumulate). Halves LDS bytes/FMA and VALU
// ops/FLOP vs fp32 float4 (R10 win: -12.7us total).

__global__ __launch_bounds__(256) void gemm1_tiled_k(const float* __restrict__ x,
                                                     const float* __restrict__ W,
                                                     const float* __restrict__ dinv,
                                                     __half* __restrict__ hws_h) {
    __shared__ hv2 Ws2[32][64];   // [k2][c]  = {W[k0+2k2][c], W[k0+2k2+1][c]}   8 KB
    __shared__ hv2 xt2[32][68];   // [k2][row]= {x[row][k0+2k2], x[row][k0+2k2+1]} 8.7 KB
    int tid = threadIdx.x;
    int row0 = blockIdx.x * TM;
    int rgrp4 = (tid >> 4) * 4;
    int cgrp4 = (tid & 15) * 4;

    float acc[4][4];
    #pragma unroll
    for (int r = 0; r < 4; ++r)
        #pragma unroll
        for (int c = 0; c < 4; ++c) acc[r][c] = 0.0f;

    for (int k0 = 0; k0 < IN_FEAT; k0 += 64) {
        // stage W pairs: 512 tasks = 32 k2 x 16 c-quads
        #pragma unroll
        for (int i = 0; i < 2; ++i) {
            int f = tid + i * 256;
            int k2 = f >> 4, c4 = (f & 15) * 4;
            float4 r0 = *(const float4*)&W[(size_t)(k0 + 2 * k2) * HIDDEN + c4];
            float4 r1 = *(const float4*)&W[(size_t)(k0 + 2 * k2 + 1) * HIDDEN + c4];
            hv8 h;
            h[0] = (_Float16)r0.x; h[1] = (_Float16)r1.x;
            h[2] = (_Float16)r0.y; h[3] = (_Float16)r1.y;
            h[4] = (_Float16)r0.z; h[5] = (_Float16)r1.z;
            h[6] = (_Float16)r0.w; h[7] = (_Float16)r1.w;
            *(hv8*)&Ws2[k2][c4] = h;
        }
        // stage x pairs: 1024 tasks = 64 rows x 16 k-quads
        #pragma unroll
        for (int i = 0; i < 4; ++i) {
            int f = tid + i * 256;
            int rr = f >> 4, kq4 = (f & 15) * 4;
            int row = row0 + rr;
            if (row >= N_NODES) row = N_NODES - 1;
            float4 v = *(const float4*)&x[(size_t)row * IN_FEAT + k0 + kq4];
            hv2 ha; ha[0] = (_Float16)v.x; ha[1] = (_Float16)v.y;
            hv2 hb; hb[0] = (_Float16)v.z; hb[1] = (_Float16)v.w;
            xt2[(kq4 >> 1) + 0][rr] = ha;
            xt2[(kq4 >> 1) + 1][rr] = hb;
        }
        __syncthreads();

        #pragma unroll 8
        for (int kk2 = 0; kk2 < 32; ++kk2) {
            hv8 av = *(const hv8*)&xt2[kk2][rgrp4];
            hv8 bv = *(const hv8*)&Ws2[kk2][cgrp4];
            hv2 a0 = __builtin_shufflevector(av, av, 0, 1);
            hv2 a1 = __builtin_shufflevector(av, av, 2, 3);
            hv2 a2 = __builtin_shufflevector(av, av, 4, 5);
            hv2 a3 = __builtin_shufflevector(av, av, 6, 7);
            hv2 b0 = __builtin_shufflevector(bv, bv, 0, 1);
            hv2 b1 = __builtin_shufflevector(bv, bv, 2, 3);
            hv2 b2 = __builtin_shufflevector(bv, bv, 4, 5);
            hv2 b3 = __builtin_shufflevector(bv, bv, 6, 7);
            acc[0][0] = FDOT2(a0, b0, acc[0][0]); acc[0][1] = FDOT2(a0, b1, acc[0][1]);
            acc[0][2] = FDOT2(a0, b2, acc[0][2]); acc[0][3] = FDOT2(a0, b3, acc[0][3]);
            acc[1][0] = FDOT2(a1, b0, acc[1][0]); acc[1][1] = FDOT2(a1, b1, acc[1][1]);
            acc[1][2] = FDOT2(a1, b2, acc[1][2]); acc[1][3] = FDOT2(a1, b3, acc[1][3]);
            acc[2][0] = FDOT2(a2, b0, acc[2][0]); acc[2][1] = FDOT2(a2, b1, acc[2][1]);
            acc[2][2] = FDOT2(a2, b2, acc[2][2]); acc[2][3] = FDOT2(a2, b3, acc[2][3]);
            acc[3][0] = FDOT2(a3, b0, acc[3][0]); acc[3][1] = FDOT2(a3, b1, acc[3][1]);
            acc[3][2] = FDOT2(a3, b2, acc[3][2]); acc[3][3] = FDOT2(a3, b3, acc[3][3]);
        }
        __syncthreads();
    }

    #pragma unroll
    for (int r = 0; r < 4; ++r) {
        int row = row0 + rgrp4 + r;
        if (row < N_NODES) {
            float dn = dinv[row];
            __half2* ph = (__half2*)&hws_h[(size_t)row * HIDDEN + cgrp4];
            ph[0] = __floats2half2_rn(acc[r][0] * dn, acc[r][1] * dn);
            ph[1] = __floats2half2_rn(acc[r][2] * dn, acc[r][3] * dn);
        }
    }
}

// ---------------- fdot2 GEMM 2: hws_h = fp16((agg_h @ W2) * dinv[row]) ----------------
// Consumes agg as RELU'D FP16 written by pull_k (bit-identical: pull_k
// stores (_Float16)fmaxf(val,0), exactly what this kernel's staging
// computed from fp32 agg). Removes 12.8MB write + 12.8MB read of fp32 agg
// from the pipeline; staging here is a straight hv8 copy.

__global__ __launch_bounds__(256) void gemm2_tiled_k(const __half* __restrict__ agg_h,
                                                     const float* __restrict__ W,
                                                     const float* __restrict__ dinv,
                                                     __half* __restrict__ hws_h) {
    __shared__ hv2 Ws2[32][64];
    __shared__ hv2 xt2[32][68];
    int tid = threadIdx.x;
    int row0 = blockIdx.x * TM;
    int rgrp4 = (tid >> 4) * 4;
    int cgrp4 = (tid & 15) * 4;

    #pragma unroll
    for (int i = 0; i < 2; ++i) {
        int f = tid + i * 256;
        int k2 = f >> 4, c4 = (f & 15) * 4;
        float4 r0 = *(const float4*)&W[(size_t)(2 * k2) * HIDDEN + c4];
        float4 r1 = *(const float4*)&W[(size_t)(2 * k2 + 1) * HIDDEN + c4];
        hv8 h;
        h[0] = (_Float16)r0.x; h[1] = (_Float16)r1.x;
        h[2] = (_Float16)r0.y; h[3] = (_Float16)r1.y;
        h[4] = (_Float16)r0.z; h[5] = (_Float16)r1.z;
        h[6] = (_Float16)r0.w; h[7] = (_Float16)r1.w;
        *(hv8*)&Ws2[k2][c4] = h;
    }
    // stage agg_h: 64 rows x 64 halves = 512 x 16B loads (2 per thread)
    #pragma unroll
    for (int i = 0; i < 2; ++i) {
        int f = tid + i * 256;
        int rr = f >> 3, kq8 = (f & 7) * 8;
        int row = row0 + rr;
        if (row >= N_NODES) row = N_NODES - 1;
        hv8 v = *(const hv8*)&agg_h[(size_t)row * HIDDEN + kq8];
        int k2 = kq8 >> 1;
        xt2[k2 + 0][rr] = __builtin_shufflevector(v, v, 0, 1);
        xt2[k2 + 1][rr] = __builtin_shufflevector(v, v, 2, 3);
        xt2[k2 + 2][rr] = __builtin_shufflevector(v, v, 4, 5);
        xt2[k2 + 3][rr] = __builtin_shufflevector(v, v, 6, 7);
    }
    __syncthreads();

    float acc[4][4];
    #pragma unroll
    for (int r = 0; r < 4; ++r)
        #pragma unroll
        for (int c = 0; c < 4; ++c) acc[r][c] = 0.0f;

    #pragma unroll 8
    for (int kk2 = 0; kk2 < 32; ++kk2) {
        hv8 av = *(const hv8*)&xt2[kk2][rgrp4];
        hv8 bv = *(const hv8*)&Ws2[kk2][cgrp4];
        hv2 a0 = __builtin_shufflevector(av, av, 0, 1);
        hv2 a1 = __builtin_shufflevector(av, av, 2, 3);
        hv2 a2 = __builtin_shufflevector(av, av, 4, 5);
        hv2 a3 = __builtin_shufflevector(av, av, 6, 7);
        hv2 b0 = __builtin_shufflevector(bv, bv, 0, 1);
        hv2 b1 = __builtin_shufflevector(bv, bv, 2, 3);
        hv2 b2 = __builtin_shufflevector(bv, bv, 4, 5);
        hv2 b3 = __builtin_shufflevector(bv, bv, 6, 7);
        acc[0][0] = FDOT2(a0, b0, acc[0][0]); acc[0][1] = FDOT2(a0, b1, acc[0][1]);
        acc[0][2] = FDOT2(a0, b2, acc[0][2]); acc[0][3] = FDOT2(a0, b3, acc[0][3]);
        acc[1][0] = FDOT2(a1, b0, acc[1][0]); acc[1][1] = FDOT2(a1, b1, acc[1][1]);
        acc[1][2] = FDOT2(a1, b2, acc[1][2]); acc[1][3] = FDOT2(a1, b3, acc[1][3]);
        acc[2][0] = FDOT2(a2, b0, acc[2][0]); acc[2][1] = FDOT2(a2, b1, acc[2][1]);
        acc[2][2] = FDOT2(a2, b2, acc[2][2]); acc[2][3] = FDOT2(a2, b3, acc[2][3]);
        acc[3][0] = FDOT2(a3, b0, acc[3][0]); acc[3][1] = FDOT2(a3, b1, acc[3][1]);
        acc[3][2] = FDOT2(a3, b2, acc[3][2]); acc[3][3] = FDOT2(a3, b3, acc[3][3]);
    }

    #pragma unroll
    for (int r = 0; r < 4; ++r) {
        int row = row0 + rgrp4 + r;
        if (row < N_NODES) {
            float dn = dinv[row];
            __half2* ph = (__half2*)&hws_h[(size_t)row * HIDDEN + cgrp4];
            ph[0] = __floats2half2_rn(acc[r][0] * dn, acc[r][1] * dn);
            ph[1] = __floats2half2_rn(acc[r][2] * dn, acc[r][3] * dn);
        }
    }
}

// ---------------- CSR pull core ----------------
// one wave per node, lane = channel, fp16 rows, uniform-base gathers,
// 16-wide gather window (A/B-verified optimum).

#define PULL_BODY(OUT_STMT)                                                  \
    int start = __builtin_amdgcn_readfirstlane(row_ptr[node]);               \
    int end   = __builtin_amdgcn_readfirstlane(row_ptr[node + 1]);           \
    const __half* __restrict__ selfrow = hws_h + ((size_t)node << 6);        \
    float blane = b[lane];                                                   \
    float a0 = __half2float(selfrow[lane]);                                  \
    float dn = dinv[node];                                                   \
    float a1 = 0.f, a2 = 0.f, a3 = 0.f, a4 = 0.f, a5 = 0.f, a6 = 0.f, a7 = 0.f; \
    int base = start;                                                        \
    while (base < end) {                                                     \
        int rem = end - base;                                                \
        int ci = base + lane;                                                \
        int lastci = end - 1;                                                \
        if (ci > lastci) ci = lastci;                                        \
        int idxv = csr_src[ci];                                              \
        int nch = rem < 64 ? rem : 64;                                       \
        for (int j = 0; j < nch; j += 16) {                                  \
            _Pragma("unroll")                                                \
            for (int k = 0; k < 16; ++k) {                                   \
                int jj = j + k;                                              \
                int s = __builtin_amdgcn_readlane(idxv, jj);                 \
                const __half* __restrict__ row = hws_h + ((size_t)s << 6);   \
                float w = (jj < rem) ? 1.f : 0.f;                            \
                float v = __half2float(row[lane]);                           \
                if (k == 0)      a0 += w * v;                                \
                else if (k == 1) a1 += w * v;                                \
                else if (k == 2) a2 += w * v;                                \
                else if (k == 3) a3 += w * v;                                \
                else if (k == 4) a4 += w * v;                                \
                else if (k == 5) a5 += w * v;                                \
                else if (k == 6) a6 += w * v;                                \
                else if (k == 7) a7 += w * v;                                \
                else if (k == 8)  a0 += w * v;                               \
                else if (k == 9)  a1 += w * v;                               \
                else if (k == 10) a2 += w * v;                               \
                else if (k == 11) a3 += w * v;                               \
                else if (k == 12) a4 += w * v;                               \
                else if (k == 13) a5 += w * v;                               \
                else if (k == 14) a6 += w * v;                               \
                else              a7 += w * v;                               \
            }                                                                \
        }                                                                    \
        base += 64;                                                          \
    }                                                                        \
    float sum = ((a0 + a1) + (a2 + a3)) + ((a4 + a5) + (a6 + a7));           \
    float val = blane + dn * sum;                                            \
    OUT_STMT

// layer-1 pull: emits RELU'D FP16 directly (bit-identical to the old
// fp32-store + gemm2-side (_Float16)fmaxf — same value, same RTNE rounding).
// WRITE_SIZE halves: 25.6MB fp32 -> 12.8MB fp16.
__global__ __launch_bounds__(256) void pull_k(const int* __restrict__ row_ptr,
                                              const int* __restrict__ csr_src,
                                              const float* __restrict__ dinv,
                                              const __half* __restrict__ hws_h,
                                              const float* __restrict__ b,
                                              __half* __restrict__ agg_h) {
    int node = __builtin_amdgcn_readfirstlane((blockIdx.x * 256 + threadIdx.x) >> 6);
    int lane = threadIdx.x & 63;
    if (node >= N_NODES) return;
    PULL_BODY({ __half* __restrict__ outrow = agg_h + ((size_t)node << 6);
                outrow[lane] = __float2half_rn(fmaxf(val, 0.0f)); })
}

// ---------------- fused pull2 + classifier head (barrier-free tail) ----------------
// R7 version verbatim (best measured). Stride-16 Wls: the 4-way tail
// conflict (3.2M cyc) is masked under the gather wall; the stride-17
// "fix" regressed 10us via codegen perturbation of the hot loop (R8).

__global__ __launch_bounds__(256) void pull_head_k(const int* __restrict__ row_ptr,
                                                   const int* __restrict__ csr_src,
                                                   const float* __restrict__ dinv,
                                                   const __half* __restrict__ hws_h,
                                                   const float* __restrict__ b,
                                                   const float* __restrict__ Wl,
                                                   const float* __restrict__ bl,
                                                   float* __restrict__ out) {
    __shared__ float Wls[HIDDEN * N_CLASSES];  // 4 KB
    __shared__ float hs[4][68];                // per-wave row, padded
    int tid = threadIdx.x;
    int wid = tid >> 6;
    int lane = tid & 63;
    int node = __builtin_amdgcn_readfirstlane(blockIdx.x * 4 + wid);

    // stage head weights once per block (256 threads x float4 = 4 KB exactly)
    ((float4*)Wls)[tid] = ((const float4*)Wl)[tid];
    __syncthreads();   // start-aligned: waves haven't diverged yet

    PULL_BODY({ hs[wid][lane] = fmaxf(val, 0.0f); })

    // same-wave LDS ordering: reads below see this wave's writes; no end
    // barrier -> no max-of-4-degree coupling.
    int kg = lane >> 4;        // 0..3
    int c  = lane & 15;
    float acc = 0.f;
    #pragma unroll
    for (int i = 0; i < 16; ++i) {
        int k = kg * 16 + i;
        acc += hs[wid][k] * Wls[k * N_CLASSES + c];
    }
    acc += __shfl_xor(acc, 16);
    acc += __shfl_xor(acc, 32);
    if (lane < 16)
        out[(size_t)node * N_CLASSES + lane] = acc + bl[lane];
}

// ---------------- launch ----------------

extern "C" void kernel_launch(void* const* d_in, const int* in_sizes, int n_in,
                              void* d_out, int out_size, void* d_ws, size_t ws_size,
                              hipStream_t stream) {
    const float* x  = (const float*)d_in[0];
    const int*   ei = (const int*)d_in[1];
    const float* W1 = (const float*)d_in[2];
    const float* b1 = (const float*)d_in[3];
    const float* W2 = (const float*)d_in[4];
    const float* b2 = (const float*)d_in[5];
    const float* Wl = (const float*)d_in[6];
    const float* bl = (const float*)d_in[7];
    float* out = (float*)d_out;

    const int* src = ei;
    const int* dst = ei + N_EDGES;

    __half* hws_h  = (__half*)d_ws;                              // N*64 halves (12.8 MB)
    __half* agg_h  = hws_h + (size_t)N_NODES * HIDDEN;           // N*64 halves (12.8 MB)
    int*   pairs_p = (int*)agg_h;                                // packed edges alias agg_h (dead before pull1 writes)
    int*   csr_src = (int*)(agg_h + (size_t)N_NODES * HIDDEN);   // E
    float* dinv    = (float*)(csr_src + N_EDGES);                // N
    int*   row_ptr = (int*)(dinv + N_NODES);                     // N+4
    int*   legacy  = row_ptr + N_NODES + 4;                      // 200 (unused)
    int*   coltot  = legacy + 400;                               // 200
    // 391x196 count/colpre matrix aliases csr_src (csr_src written later by fine2)
    int*   blk_cnt = csr_src;

    // --- CSR build (deterministic, atomic-free partition; 4 kernels) ---
    count_k<<<NCB, 256, 0, stream>>>(dst, blk_cnt);
    colscan_k<<<NBUK, 512, 0, stream>>>(blk_cnt, coltot);
    place_k<<<NCB, 256, 0, stream>>>(src, dst, blk_cnt, coltot, pairs_p);
    fine2_k<<<NBUK, 256, 0, stream>>>(pairs_p, coltot, csr_src, row_ptr, dinv);

    // --- layer 1 ---
    gemm1_tiled_k<<<GBLK, 256, 0, stream>>>(x, W1, dinv, hws_h);
    pull_k<<<(N_NODES * 64 + 255) / 256, 256, 0, stream>>>(row_ptr, csr_src, dinv,
                                                           hws_h, b1, agg_h);

    // --- layer 2 (+ fused classifier head) ---
    gemm2_tiled_k<<<GBLK, 256, 0, stream>>>(agg_h, W2, dinv, hws_h);
    pull_head_k<<<N_NODES / 4, 256, 0, stream>>>(row_ptr, csr_src, dinv,
                                                 hws_h, b2, Wl, bl, out);
}